// Round 1
// baseline (9495.417 us; speedup 1.0000x reference)
//
#include <hip/hip_runtime.h>
#include <hip/hip_bf16.h>
#include <math.h>

// Problem constants
#define Bb 2
#define Ss 2048
#define Dd 1024
#define Hh 16
#define FFf 4096
#define DHh 64
#define EPSf 1e-5f
#define SCALEf 0.03125f   // 1/sqrt(1024)

// ---------------------------------------------------------------------------
// LayerNorm: one row (D=1024) per 256-thread block, float4 per thread.
// ---------------------------------------------------------------------------
__global__ __launch_bounds__(256) void layernorm_k(const float* __restrict__ X,
                                                   const float* __restrict__ g,
                                                   const float* __restrict__ bta,
                                                   float* __restrict__ Y) {
    __shared__ float red[8];
    const int row = blockIdx.x;
    const int tid = threadIdx.x;
    const size_t base = (size_t)row * Dd + tid * 4;
    const float4 xv = *(const float4*)&X[base];
    float s  = xv.x + xv.y + xv.z + xv.w;
    float sq = xv.x * xv.x + xv.y * xv.y + xv.z * xv.z + xv.w * xv.w;
#pragma unroll
    for (int o = 32; o >= 1; o >>= 1) {
        s  += __shfl_xor(s, o, 64);
        sq += __shfl_xor(sq, o, 64);
    }
    const int lane = tid & 63, wv = tid >> 6;
    if (lane == 0) { red[wv] = s; red[4 + wv] = sq; }
    __syncthreads();
    const float tot  = red[0] + red[1] + red[2] + red[3];
    const float totq = red[4] + red[5] + red[6] + red[7];
    const float mu  = tot * (1.0f / Dd);
    const float var = totq * (1.0f / Dd) - mu * mu;
    const float inv = 1.0f / sqrtf(var + EPSf);
    const float4 gv = *(const float4*)&g[tid * 4];
    const float4 bv = *(const float4*)&bta[tid * 4];
    float4 o;
    o.x = (xv.x - mu) * inv * gv.x + bv.x;
    o.y = (xv.y - mu) * inv * gv.y + bv.y;
    o.z = (xv.z - mu) * inv * gv.z + bv.z;
    o.w = (xv.w - mu) * inv * gv.w + bv.w;
    *(float4*)&Y[base] = o;
}

// ---------------------------------------------------------------------------
// fp32 tiled GEMM: C[M,N] = A[M,K] @ W[K,N] (+ R) (optionally exact GELU)
// BM=BN=64, BK=16, 256 threads, 4x4 per thread.
// ---------------------------------------------------------------------------
__device__ __forceinline__ float gelu_exact(float v) {
    return 0.5f * v * (1.0f + erff(v * 0.7071067811865475f));
}

__global__ __launch_bounds__(256) void gemm_f32(const float* __restrict__ A,
                                                const float* __restrict__ W,
                                                const float* __restrict__ R,
                                                float* __restrict__ C,
                                                int M, int N, int K, int do_gelu) {
    __shared__ float As[16][68];   // [k][m], padded for alignment/banks
    __shared__ float Bs[16][64];   // [k][n]
    const int tid = threadIdx.x;
    const int bx = blockIdx.x;     // N tiles
    const int by = blockIdx.y;     // M tiles
    const int tx = tid & 15, ty = tid >> 4;
    const int col0 = bx * 64 + tx * 4;
    // staging indices
    const int ar = tid >> 2;          // 0..63 (row in A tile)
    const int ac = (tid & 3) * 4;     // 0,4,8,12 (k in A tile)
    const int br = tid >> 4;          // 0..15 (k in B tile)
    const int bc = (tid & 15) * 4;    // 0..60 (col in B tile)

    float acc[4][4] = {};
    for (int k0 = 0; k0 < K; k0 += 16) {
        const float4 av = *(const float4*)&A[(size_t)(by * 64 + ar) * K + k0 + ac];
        const float4 bv = *(const float4*)&W[(size_t)(k0 + br) * N + bx * 64 + bc];
        __syncthreads();
        As[ac + 0][ar] = av.x;
        As[ac + 1][ar] = av.y;
        As[ac + 2][ar] = av.z;
        As[ac + 3][ar] = av.w;
        *(float4*)&Bs[br][bc] = bv;
        __syncthreads();
#pragma unroll
        for (int kk = 0; kk < 16; ++kk) {
            const float4 a4 = *(const float4*)&As[kk][ty * 4];
            const float4 b4 = *(const float4*)&Bs[kk][tx * 4];
            const float a[4] = {a4.x, a4.y, a4.z, a4.w};
            const float b[4] = {b4.x, b4.y, b4.z, b4.w};
#pragma unroll
            for (int i = 0; i < 4; ++i)
#pragma unroll
                for (int j = 0; j < 4; ++j) acc[i][j] += a[i] * b[j];
        }
    }
    const int row0 = by * 64 + ty * 4;
#pragma unroll
    for (int i = 0; i < 4; ++i) {
        const int row = row0 + i;
        float4 o = make_float4(acc[i][0], acc[i][1], acc[i][2], acc[i][3]);
        if (R) {
            const float4 r4 = *(const float4*)&R[(size_t)row * N + col0];
            o.x += r4.x; o.y += r4.y; o.z += r4.z; o.w += r4.w;
        }
        if (do_gelu) {
            o.x = gelu_exact(o.x); o.y = gelu_exact(o.y);
            o.z = gelu_exact(o.z); o.w = gelu_exact(o.w);
        }
        *(float4*)&C[(size_t)row * N + col0] = o;
    }
}

// ---------------------------------------------------------------------------
// Flash attention fp32: one wave per query row, online softmax over all keys.
// Q,K,V layout: [B*S][D] where column = h*64 + d. lane = d.
// ---------------------------------------------------------------------------
__global__ __launch_bounds__(256) void attn_flash(const float* __restrict__ Q,
                                                  const float* __restrict__ K,
                                                  const float* __restrict__ V,
                                                  const float* __restrict__ mask,
                                                  float* __restrict__ O) {
    const int widx = threadIdx.x >> 6;
    const int lane = threadIdx.x & 63;
    const unsigned w = blockIdx.x * 4 + widx;   // 0 .. B*H*S-1, q fastest
    const int qi = w & (Ss - 1);
    const int h  = (w >> 11) & (Hh - 1);
    const int b  = w >> 15;

    const size_t headoff = ((size_t)b * Ss * Hh + h) * DHh + lane;
    const float* kbase = K + headoff;          // + k*1024
    const float* vbase = V + headoff;
    const float qv = Q[(((size_t)b * Ss + qi) * Hh + h) * DHh + lane];
    const float* mrow = mask + (size_t)b * Ss;

    float m = -INFINITY, l = 0.0f, acc = 0.0f;
    for (int k = 0; k < Ss; k += 4) {
        float s0 = qv * kbase[(size_t)(k + 0) * Dd];
        float s1 = qv * kbase[(size_t)(k + 1) * Dd];
        float s2 = qv * kbase[(size_t)(k + 2) * Dd];
        float s3 = qv * kbase[(size_t)(k + 3) * Dd];
#pragma unroll
        for (int o = 32; o >= 1; o >>= 1) {
            s0 += __shfl_xor(s0, o, 64);
            s1 += __shfl_xor(s1, o, 64);
            s2 += __shfl_xor(s2, o, 64);
            s3 += __shfl_xor(s3, o, 64);
        }
        s0 = s0 * SCALEf + mrow[k + 0];
        s1 = s1 * SCALEf + mrow[k + 1];
        s2 = s2 * SCALEf + mrow[k + 2];
        s3 = s3 * SCALEf + mrow[k + 3];
        const float mx = fmaxf(fmaxf(s0, s1), fmaxf(s2, s3));
        const float m_new = fmaxf(m, mx);
        const float corr = __expf(m - m_new);   // exp(-inf)=0 on first iter
        const float p0 = __expf(s0 - m_new);
        const float p1 = __expf(s1 - m_new);
        const float p2 = __expf(s2 - m_new);
        const float p3 = __expf(s3 - m_new);
        l = l * corr + (p0 + p1 + p2 + p3);
        const float v0 = vbase[(size_t)(k + 0) * Dd];
        const float v1 = vbase[(size_t)(k + 1) * Dd];
        const float v2 = vbase[(size_t)(k + 2) * Dd];
        const float v3 = vbase[(size_t)(k + 3) * Dd];
        acc = acc * corr + p0 * v0 + p1 * v1 + p2 * v2 + p3 * v3;
        m = m_new;
    }
    O[(((size_t)b * Ss + qi) * Hh + h) * DHh + lane] = acc / l;
}

// ---------------------------------------------------------------------------
extern "C" void kernel_launch(void* const* d_in, const int* in_sizes, int n_in,
                              void* d_out, int out_size, void* d_ws, size_t ws_size,
                              hipStream_t stream) {
    const float* x    = (const float*)d_in[0];
    const float* mask = (const float*)d_in[1];
    const float* wq   = (const float*)d_in[2];
    const float* wk   = (const float*)d_in[3];
    const float* wv   = (const float*)d_in[4];
    const float* wo   = (const float*)d_in[5];
    const float* w1   = (const float*)d_in[6];
    const float* w2   = (const float*)d_in[7];
    const float* ln1g = (const float*)d_in[8];
    const float* ln1b = (const float*)d_in[9];
    const float* ln2g = (const float*)d_in[10];
    const float* ln2b = (const float*)d_in[11];
    float* out = (float*)d_out;

    float* ws = (float*)d_ws;
    const size_t TOK = (size_t)Bb * Ss;          // 4096 rows
    const size_t MAT = TOK * Dd;                 // 4,194,304 floats
    float* y    = ws;                            // LN1 out     [MAT]
    float* q    = ws + MAT;                      // Q           [MAT]
    float* kbuf = ws + 2 * MAT;                  // K           [MAT]
    float* vbuf = ws + 3 * MAT;                  // V           [MAT]
    float* attn = ws;                            // reuse y     [MAT]
    float* y2   = ws + MAT;                      // reuse q     [MAT]
    float* hbuf = ws + 2 * MAT;                  // FFN mid     [TOK*FF]

    const int M = (int)TOK;                      // 4096

    // LN1
    layernorm_k<<<M, 256, 0, stream>>>(x, ln1g, ln1b, y);
    // QKV projections
    dim3 gD(Dd / 64, M / 64);
    gemm_f32<<<gD, 256, 0, stream>>>(y, wq, nullptr, q,    M, Dd, Dd, 0);
    gemm_f32<<<gD, 256, 0, stream>>>(y, wk, nullptr, kbuf, M, Dd, Dd, 0);
    gemm_f32<<<gD, 256, 0, stream>>>(y, wv, nullptr, vbuf, M, Dd, Dd, 0);
    // attention (one wave per q row)
    attn_flash<<<(Bb * Hh * Ss) / 4, 256, 0, stream>>>(q, kbuf, vbuf, mask, attn);
    // out proj + residual -> d_out (x_mid)
    gemm_f32<<<gD, 256, 0, stream>>>(attn, wo, x, out, M, Dd, Dd, 0);
    // LN2
    layernorm_k<<<M, 256, 0, stream>>>(out, ln2g, ln2b, y2);
    // FFN
    dim3 gF(FFf / 64, M / 64);
    gemm_f32<<<gF, 256, 0, stream>>>(y2, w1, nullptr, hbuf, M, FFf, Dd, 1);
    gemm_f32<<<gD, 256, 0, stream>>>(hbuf, w2, out, out, M, Dd, FFf, 0);
}

// Round 2
// 1575.783 us; speedup vs baseline: 6.0258x; 6.0258x over previous
//
#include <hip/hip_runtime.h>
#include <hip/hip_bf16.h>
#include <math.h>

// Problem constants
#define Bb 2
#define Ss 2048
#define Dd 1024
#define Hh 16
#define FFf 4096
#define DHh 64
#define EPSf 1e-5f
#define SCALEf 0.03125f   // 1/sqrt(1024)

typedef short s16x8 __attribute__((ext_vector_type(8)));
typedef short s16x4 __attribute__((ext_vector_type(4)));
typedef float f32x4 __attribute__((ext_vector_type(4)));

// fp32 -> bf16 (RNE) as raw short
__device__ __forceinline__ short f2bs(float f) {
    union { float f; unsigned u; } v; v.f = f;
    const unsigned r = (v.u + 0x7FFFu + ((v.u >> 16) & 1u)) >> 16;
    return (short)r;
}

// ---------------------------------------------------------------------------
// LayerNorm: one row (D=1024) per 256-thread block, float4 per thread.
// ---------------------------------------------------------------------------
__global__ __launch_bounds__(256) void layernorm_k(const float* __restrict__ X,
                                                   const float* __restrict__ g,
                                                   const float* __restrict__ bta,
                                                   float* __restrict__ Y) {
    __shared__ float red[8];
    const int row = blockIdx.x;
    const int tid = threadIdx.x;
    const size_t base = (size_t)row * Dd + tid * 4;
    const float4 xv = *(const float4*)&X[base];
    float s  = xv.x + xv.y + xv.z + xv.w;
    float sq = xv.x * xv.x + xv.y * xv.y + xv.z * xv.z + xv.w * xv.w;
#pragma unroll
    for (int o = 32; o >= 1; o >>= 1) {
        s  += __shfl_xor(s, o, 64);
        sq += __shfl_xor(sq, o, 64);
    }
    const int lane = tid & 63, wv = tid >> 6;
    if (lane == 0) { red[wv] = s; red[4 + wv] = sq; }
    __syncthreads();
    const float tot  = red[0] + red[1] + red[2] + red[3];
    const float totq = red[4] + red[5] + red[6] + red[7];
    const float mu  = tot * (1.0f / Dd);
    const float var = totq * (1.0f / Dd) - mu * mu;
    const float inv = 1.0f / sqrtf(var + EPSf);
    const float4 gv = *(const float4*)&g[tid * 4];
    const float4 bv = *(const float4*)&bta[tid * 4];
    float4 o;
    o.x = (xv.x - mu) * inv * gv.x + bv.x;
    o.y = (xv.y - mu) * inv * gv.y + bv.y;
    o.z = (xv.z - mu) * inv * gv.z + bv.z;
    o.w = (xv.w - mu) * inv * gv.w + bv.w;
    *(float4*)&Y[base] = o;
}

// ---------------------------------------------------------------------------
// fp32 tiled GEMM: C[M,N] = A[M,K] @ W[K,N] (+ R) (optionally exact GELU)
// ---------------------------------------------------------------------------
__device__ __forceinline__ float gelu_exact(float v) {
    return 0.5f * v * (1.0f + erff(v * 0.7071067811865475f));
}

__global__ __launch_bounds__(256) void gemm_f32(const float* __restrict__ A,
                                                const float* __restrict__ W,
                                                const float* __restrict__ R,
                                                float* __restrict__ C,
                                                int M, int N, int K, int do_gelu) {
    __shared__ float As[16][68];
    __shared__ float Bs[16][64];
    const int tid = threadIdx.x;
    const int bx = blockIdx.x;
    const int by = blockIdx.y;
    const int tx = tid & 15, ty = tid >> 4;
    const int col0 = bx * 64 + tx * 4;
    const int ar = tid >> 2;
    const int ac = (tid & 3) * 4;
    const int br = tid >> 4;
    const int bc = (tid & 15) * 4;

    float acc[4][4] = {};
    for (int k0 = 0; k0 < K; k0 += 16) {
        const float4 av = *(const float4*)&A[(size_t)(by * 64 + ar) * K + k0 + ac];
        const float4 bv = *(const float4*)&W[(size_t)(k0 + br) * N + bx * 64 + bc];
        __syncthreads();
        As[ac + 0][ar] = av.x;
        As[ac + 1][ar] = av.y;
        As[ac + 2][ar] = av.z;
        As[ac + 3][ar] = av.w;
        *(float4*)&Bs[br][bc] = bv;
        __syncthreads();
#pragma unroll
        for (int kk = 0; kk < 16; ++kk) {
            const float4 a4 = *(const float4*)&As[kk][ty * 4];
            const float4 b4 = *(const float4*)&Bs[kk][tx * 4];
            const float a[4] = {a4.x, a4.y, a4.z, a4.w};
            const float b[4] = {b4.x, b4.y, b4.z, b4.w};
#pragma unroll
            for (int i = 0; i < 4; ++i)
#pragma unroll
                for (int j = 0; j < 4; ++j) acc[i][j] += a[i] * b[j];
        }
    }
    const int row0 = by * 64 + ty * 4;
#pragma unroll
    for (int i = 0; i < 4; ++i) {
        const int row = row0 + i;
        float4 o = make_float4(acc[i][0], acc[i][1], acc[i][2], acc[i][3]);
        if (R) {
            const float4 r4 = *(const float4*)&R[(size_t)row * N + col0];
            o.x += r4.x; o.y += r4.y; o.z += r4.z; o.w += r4.w;
        }
        if (do_gelu) {
            o.x = gelu_exact(o.x); o.y = gelu_exact(o.y);
            o.z = gelu_exact(o.z); o.w = gelu_exact(o.w);
        }
        *(float4*)&C[(size_t)row * N + col0] = o;
    }
}

// ---------------------------------------------------------------------------
// MFMA bf16 flash attention.
// Block = 4 waves = 64 queries of one (b,h); KBLK=64 keys per chunk.
// Wave: 16 queries. QK^T and PV via mfma_f32_16x16x32_bf16.
// k-mapping for A and B operands uses the same kappa(l,i) = (l>>4)*8+i (+32*half)
// => permutation-invariant, correct for any HW internal k-order.
// C/D layout (HW-verified): col = lane&15, row = (lane>>4)*4 + reg.
// ---------------------------------------------------------------------------
__global__ __launch_bounds__(256) void attn_mfma(const float* __restrict__ Q,
                                                 const float* __restrict__ K,
                                                 const float* __restrict__ V,
                                                 const float* __restrict__ mask,
                                                 float* __restrict__ O) {
    __shared__ short Kl[64][72];      // [k][d]  (+8 pad)
    __shared__ short Vt[64][72];      // [d][k]  (+8 pad)
    __shared__ short Pl[4][16][72];   // per-wave P [q][k]

    const int tid  = threadIdx.x;
    const int wv   = tid >> 6;
    const int lane = tid & 63;
    const int lg   = lane >> 4;
    const int lr   = lane & 15;

    const int bid = blockIdx.x;
    const int qt = bid & 31;
    const int h  = (bid >> 5) & 15;
    const int b  = bid >> 9;

    const int q0 = qt * 64 + wv * 16;

    // Q fragments (A-operand): row = lr, d = half*32 + lg*8 + i
    s16x8 qf[2];
    {
        const float* qsrc = Q + ((size_t)(b * Ss + q0 + lr)) * Dd + h * 64 + lg * 8;
#pragma unroll
        for (int half = 0; half < 2; ++half) {
            const float4 v0 = *(const float4*)(qsrc + half * 32);
            const float4 v1 = *(const float4*)(qsrc + half * 32 + 4);
            s16x8 f;
            f[0] = f2bs(v0.x); f[1] = f2bs(v0.y); f[2] = f2bs(v0.z); f[3] = f2bs(v0.w);
            f[4] = f2bs(v1.x); f[5] = f2bs(v1.y); f[6] = f2bs(v1.z); f[7] = f2bs(v1.w);
            qf[half] = f;
        }
    }

    const float* mrow = mask + (size_t)b * Ss;

    f32x4 o_acc[4] = {};
    float m_run[4], l_run[4];
#pragma unroll
    for (int r = 0; r < 4; ++r) { m_run[r] = -INFINITY; l_run[r] = 0.0f; }

    const int srow = tid >> 2;          // staging: k row 0..63
    const int sdc  = (tid & 3) * 16;    // staging: d base 0/16/32/48

    for (int kc = 0; kc < Ss / 64; ++kc) {
        // ---- stage K (row-major) and V (transposed) as bf16 ----
        const float* ksrc = K + ((size_t)(b * Ss + kc * 64 + srow)) * Dd + h * 64 + sdc;
        const float* vsrc = V + ((size_t)(b * Ss + kc * 64 + srow)) * Dd + h * 64 + sdc;
#pragma unroll
        for (int j = 0; j < 4; ++j) {
            const float4 kv = *(const float4*)(ksrc + j * 4);
            s16x4 kw;
            kw[0] = f2bs(kv.x); kw[1] = f2bs(kv.y); kw[2] = f2bs(kv.z); kw[3] = f2bs(kv.w);
            *(s16x4*)&Kl[srow][sdc + j * 4] = kw;
            const float4 vv = *(const float4*)(vsrc + j * 4);
            Vt[sdc + j * 4 + 0][srow] = f2bs(vv.x);
            Vt[sdc + j * 4 + 1][srow] = f2bs(vv.y);
            Vt[sdc + j * 4 + 2][srow] = f2bs(vv.z);
            Vt[sdc + j * 4 + 3][srow] = f2bs(vv.w);
        }
        __syncthreads();

        // ---- QK^T: S[16q][64k] = 4 kt-tiles ----
        f32x4 s[4];
#pragma unroll
        for (int kt = 0; kt < 4; ++kt) {
            f32x4 acc = {};
#pragma unroll
            for (int half = 0; half < 2; ++half) {
                const s16x8 bk = *(const s16x8*)&Kl[kt * 16 + lr][half * 32 + lg * 8];
                acc = __builtin_amdgcn_mfma_f32_16x16x32_bf16(qf[half], bk, acc, 0, 0, 0);
            }
            s[kt] = acc;
        }

        // ---- scale + mask, row max ----
        float mt[4];
#pragma unroll
        for (int r = 0; r < 4; ++r) mt[r] = -INFINITY;
#pragma unroll
        for (int kt = 0; kt < 4; ++kt) {
            const float mv = mrow[kc * 64 + kt * 16 + lr];
#pragma unroll
            for (int r = 0; r < 4; ++r) {
                s[kt][r] = s[kt][r] * SCALEf + mv;
                mt[r] = fmaxf(mt[r], s[kt][r]);
            }
        }
#pragma unroll
        for (int o = 1; o <= 8; o <<= 1) {
#pragma unroll
            for (int r = 0; r < 4; ++r) mt[r] = fmaxf(mt[r], __shfl_xor(mt[r], o, 64));
        }

        // ---- online softmax update ----
        float corr[4], rs[4];
#pragma unroll
        for (int r = 0; r < 4; ++r) {
            const float mn = fmaxf(m_run[r], mt[r]);
            corr[r] = __expf(m_run[r] - mn);
            m_run[r] = mn;
            rs[r] = 0.0f;
        }
#pragma unroll
        for (int kt = 0; kt < 4; ++kt) {
#pragma unroll
            for (int r = 0; r < 4; ++r) {
                const float p = __expf(s[kt][r] - m_run[r]);
                rs[r] += p;
                Pl[wv][lg * 4 + r][kt * 16 + lr] = f2bs(p);
            }
        }
#pragma unroll
        for (int o = 1; o <= 8; o <<= 1) {
#pragma unroll
            for (int r = 0; r < 4; ++r) rs[r] += __shfl_xor(rs[r], o, 64);
        }
#pragma unroll
        for (int r = 0; r < 4; ++r) l_run[r] = l_run[r] * corr[r] + rs[r];
#pragma unroll
        for (int dt = 0; dt < 4; ++dt) {
#pragma unroll
            for (int r = 0; r < 4; ++r) o_acc[dt][r] *= corr[r];
        }

        // ---- PV: O[16q][64d] += P @ V ----
#pragma unroll
        for (int kh = 0; kh < 2; ++kh) {
            const s16x8 pa = *(const s16x8*)&Pl[wv][lr][kh * 32 + lg * 8];
#pragma unroll
            for (int dt = 0; dt < 4; ++dt) {
                const s16x8 bv = *(const s16x8*)&Vt[dt * 16 + lr][kh * 32 + lg * 8];
                o_acc[dt] = __builtin_amdgcn_mfma_f32_16x16x32_bf16(pa, bv, o_acc[dt], 0, 0, 0);
            }
        }
        __syncthreads();
    }

    // ---- epilogue: O = acc / l ----
#pragma unroll
    for (int r = 0; r < 4; ++r) {
        const float inv = 1.0f / l_run[r];
        float* orow = O + ((size_t)(b * Ss + q0 + lg * 4 + r)) * Dd + h * 64 + lr;
#pragma unroll
        for (int dt = 0; dt < 4; ++dt) orow[dt * 16] = o_acc[dt][r] * inv;
    }
}

// ---------------------------------------------------------------------------
extern "C" void kernel_launch(void* const* d_in, const int* in_sizes, int n_in,
                              void* d_out, int out_size, void* d_ws, size_t ws_size,
                              hipStream_t stream) {
    const float* x    = (const float*)d_in[0];
    const float* mask = (const float*)d_in[1];
    const float* wq   = (const float*)d_in[2];
    const float* wk   = (const float*)d_in[3];
    const float* wv   = (const float*)d_in[4];
    const float* wo   = (const float*)d_in[5];
    const float* w1   = (const float*)d_in[6];
    const float* w2   = (const float*)d_in[7];
    const float* ln1g = (const float*)d_in[8];
    const float* ln1b = (const float*)d_in[9];
    const float* ln2g = (const float*)d_in[10];
    const float* ln2b = (const float*)d_in[11];
    float* out = (float*)d_out;

    float* ws = (float*)d_ws;
    const size_t TOK = (size_t)Bb * Ss;          // 4096 rows
    const size_t MAT = TOK * Dd;
    float* y    = ws;
    float* q    = ws + MAT;
    float* kbuf = ws + 2 * MAT;
    float* vbuf = ws + 3 * MAT;
    float* attn = ws;                            // reuse y
    float* y2   = ws + MAT;                      // reuse q
    float* hbuf = ws + 2 * MAT;                  // FFN mid [TOK*FF]

    const int M = (int)TOK;

    layernorm_k<<<M, 256, 0, stream>>>(x, ln1g, ln1b, y);
    dim3 gD(Dd / 64, M / 64);
    gemm_f32<<<gD, 256, 0, stream>>>(y, wq, nullptr, q,    M, Dd, Dd, 0);
    gemm_f32<<<gD, 256, 0, stream>>>(y, wk, nullptr, kbuf, M, Dd, Dd, 0);
    gemm_f32<<<gD, 256, 0, stream>>>(y, wv, nullptr, vbuf, M, Dd, Dd, 0);
    // MFMA flash attention: 1024 blocks (b,h,qtile)
    attn_mfma<<<Bb * Hh * (Ss / 64), 256, 0, stream>>>(q, kbuf, vbuf, mask, attn);
    gemm_f32<<<gD, 256, 0, stream>>>(attn, wo, x, out, M, Dd, Dd, 0);
    layernorm_k<<<M, 256, 0, stream>>>(out, ln2g, ln2b, y2);
    dim3 gF(FFf / 64, M / 64);
    gemm_f32<<<gF, 256, 0, stream>>>(y2, w1, nullptr, hbuf, M, FFf, Dd, 1);
    gemm_f32<<<gD, 256, 0, stream>>>(hbuf, w2, out, out, M, Dd, FFf, 0);
}

// Round 3
// 391.759 us; speedup vs baseline: 24.2379x; 4.0223x over previous
//
#include <hip/hip_runtime.h>
#include <hip/hip_bf16.h>
#include <math.h>

// Problem constants
#define Bb 2
#define Ss 2048
#define Dd 1024
#define Hh 16
#define FFf 4096
#define EPSf 1e-5f
#define SCALEf 0.03125f   // 1/sqrt(1024)

typedef short s16x8 __attribute__((ext_vector_type(8)));
typedef short s16x4 __attribute__((ext_vector_type(4)));
typedef float f32x4 __attribute__((ext_vector_type(4)));

// fp32 -> bf16 (RNE) raw bits
__device__ __forceinline__ short f2bs(float f) {
    union { float f; unsigned u; } v; v.f = f;
    const unsigned r = (v.u + 0x7FFFu + ((v.u >> 16) & 1u)) >> 16;
    return (short)r;
}
__device__ __forceinline__ float gelu_exact(float v) {
    return 0.5f * v * (1.0f + erff(v * 0.7071067811865475f));
}
// async global->LDS, 16B per lane; LDS dest is wave-uniform base + lane*16
__device__ __forceinline__ void gload16(const void* g, void* l) {
    __builtin_amdgcn_global_load_lds(
        (const __attribute__((address_space(1))) unsigned int*)g,
        (__attribute__((address_space(3))) unsigned int*)l, 16, 0, 0);
}

// ---------------------------------------------------------------------------
// Weight transpose + fp32->bf16: W[K][N] f32 -> Wt[N][K] bf16
// grid(N/64, K/64), 256 threads
// ---------------------------------------------------------------------------
__global__ __launch_bounds__(256) void transpose_w(const float* __restrict__ W,
                                                   short* __restrict__ Wt,
                                                   int K, int N) {
    __shared__ short T[64][65];
    const int tid = threadIdx.x;
    const int n0 = blockIdx.x * 64, k0 = blockIdx.y * 64;
    const int c = tid & 63, rg = tid >> 6;
#pragma unroll
    for (int j = 0; j < 16; ++j) {
        const int r = rg * 16 + j;
        T[r][c] = f2bs(W[(size_t)(k0 + r) * N + n0 + c]);
    }
    __syncthreads();
#pragma unroll
    for (int j = 0; j < 16; ++j) {
        const int r = rg * 16 + j;
        Wt[(size_t)(n0 + r) * K + k0 + c] = T[c][r];
    }
}

// ---------------------------------------------------------------------------
// LayerNorm: one row per 256-thread block, fp32 in, bf16 out.
// ---------------------------------------------------------------------------
__global__ __launch_bounds__(256) void layernorm_bf16(const float* __restrict__ X,
                                                      const float* __restrict__ g,
                                                      const float* __restrict__ bta,
                                                      short* __restrict__ Y) {
    __shared__ float red[8];
    const int row = blockIdx.x;
    const int tid = threadIdx.x;
    const size_t base = (size_t)row * Dd + tid * 4;
    const float4 xv = *(const float4*)&X[base];
    float s  = xv.x + xv.y + xv.z + xv.w;
    float sq = xv.x * xv.x + xv.y * xv.y + xv.z * xv.z + xv.w * xv.w;
#pragma unroll
    for (int o = 32; o >= 1; o >>= 1) {
        s  += __shfl_xor(s, o, 64);
        sq += __shfl_xor(sq, o, 64);
    }
    const int lane = tid & 63, wv = tid >> 6;
    if (lane == 0) { red[wv] = s; red[4 + wv] = sq; }
    __syncthreads();
    const float tot  = red[0] + red[1] + red[2] + red[3];
    const float totq = red[4] + red[5] + red[6] + red[7];
    const float mu  = tot * (1.0f / Dd);
    const float var = totq * (1.0f / Dd) - mu * mu;
    const float inv = 1.0f / sqrtf(var + EPSf);
    const float4 gv = *(const float4*)&g[tid * 4];
    const float4 bv = *(const float4*)&bta[tid * 4];
    s16x4 o;
    o[0] = f2bs((xv.x - mu) * inv * gv.x + bv.x);
    o[1] = f2bs((xv.y - mu) * inv * gv.y + bv.y);
    o[2] = f2bs((xv.z - mu) * inv * gv.z + bv.z);
    o[3] = f2bs((xv.w - mu) * inv * gv.w + bv.w);
    *(s16x4*)&Y[base] = o;
}

// ---------------------------------------------------------------------------
// bf16 MFMA GEMM (m97 structure): C[M,N] = A[M,K] @ Bt[N,K]^T
// 128x128 tile, BK=32, 256 thr (4 waves 2x2), 4x4 frags of 16x16x32 per wave.
// EPI: 0 = bf16 out, 1 = GELU + bf16 out, 2 = +R (fp32) -> fp32 out
// ---------------------------------------------------------------------------
template <int EPI>
__global__ __launch_bounds__(256) void gemm_bf16(const short* __restrict__ A,
                                                 const short* __restrict__ Bt,
                                                 const float* __restrict__ R,
                                                 void* __restrict__ Cout,
                                                 int M, int N, int K) {
    __shared__ short As[128 * 32];
    __shared__ short Bs[128 * 32];
    const int tid = threadIdx.x;
    const int w = tid >> 6, l = tid & 63;
    const int lr = l & 15, lg = l >> 4;
    const int wr = w >> 1, wc = w & 1;
    const int bx = blockIdx.x, by = blockIdx.y;

    const int srow = l >> 2;        // row within 16-row staging group
    const int skb  = (l & 3) * 8;   // k element offset 0/8/16/24
    const size_t arow0 = (size_t)(by * 128 + w * 32);
    const size_t brow0 = (size_t)(bx * 128 + w * 32);

    f32x4 acc[4][4] = {};

    for (int k0 = 0; k0 < K; k0 += 32) {
        __syncthreads();
#pragma unroll
        for (int j = 0; j < 2; ++j) {
            gload16(A + (arow0 + j * 16 + srow) * K + k0 + skb,
                    &As[(w * 32 + j * 16) * 32]);
            gload16(Bt + (brow0 + j * 16 + srow) * K + k0 + skb,
                    &Bs[(w * 32 + j * 16) * 32]);
        }
        __syncthreads();
        s16x8 a[4], b[4];
#pragma unroll
        for (int m = 0; m < 4; ++m)
            a[m] = *(const s16x8*)&As[(wr * 64 + m * 16 + lr) * 32 + lg * 8];
#pragma unroll
        for (int n = 0; n < 4; ++n)
            b[n] = *(const s16x8*)&Bs[(wc * 64 + n * 16 + lr) * 32 + lg * 8];
#pragma unroll
        for (int m = 0; m < 4; ++m)
#pragma unroll
            for (int n = 0; n < 4; ++n)
                acc[m][n] = __builtin_amdgcn_mfma_f32_16x16x32_bf16(a[m], b[n], acc[m][n], 0, 0, 0);
    }

    const int row0 = by * 128 + wr * 64;
    const int col0 = bx * 128 + wc * 64;
#pragma unroll
    for (int m = 0; m < 4; ++m) {
#pragma unroll
        for (int r = 0; r < 4; ++r) {
            const int row = row0 + m * 16 + lg * 4 + r;
#pragma unroll
            for (int n = 0; n < 4; ++n) {
                const int col = col0 + n * 16 + lr;
                float v = acc[m][n][r];
                if (EPI == 1) v = gelu_exact(v);
                if (EPI == 2) {
                    float* C = (float*)Cout;
                    C[(size_t)row * N + col] = v + R[(size_t)row * N + col];
                } else {
                    ((short*)Cout)[(size_t)row * N + col] = f2bs(v);
                }
            }
        }
    }
}

// ---------------------------------------------------------------------------
// MFMA bf16 flash attention. QKV fused buffer [B*S][3072] = [Q|K|V] bf16.
// Block = 4 waves = 64 queries of one (b,h); KBLK=64.
// C/D layout: col=lane&15, row=(lane>>4)*4+reg. Same-kappa trick for k-dim.
// ---------------------------------------------------------------------------
__global__ __launch_bounds__(256) void attn_mfma(const short* __restrict__ QKV,
                                                 const float* __restrict__ mask,
                                                 short* __restrict__ Oa) {
    __shared__ short Kl[64][72];
    __shared__ short Vt[64][72];
    __shared__ short Pl[4][16][72];

    const int tid  = threadIdx.x;
    const int wv   = tid >> 6;
    const int lane = tid & 63;
    const int lg   = lane >> 4;
    const int lr   = lane & 15;

    const int bid = blockIdx.x;
    const int qt = bid & 31;
    const int h  = (bid >> 5) & 15;
    const int b  = bid >> 9;
    const int q0 = qt * 64 + wv * 16;

    // Q fragments: row=lr, k(d) = half*32 + lg*8 + i
    s16x8 qf[2];
    {
        const short* qsrc = QKV + ((size_t)(b * Ss + q0 + lr)) * 3072 + h * 64 + lg * 8;
        qf[0] = *(const s16x8*)(qsrc);
        qf[1] = *(const s16x8*)(qsrc + 32);
    }
    const float* mrow = mask + (size_t)b * Ss;

    f32x4 o_acc[4] = {};
    float m_run[4], l_run[4];
#pragma unroll
    for (int r = 0; r < 4; ++r) { m_run[r] = -INFINITY; l_run[r] = 0.0f; }

    const int srow = tid >> 2;
    const int sdc  = (tid & 3) * 16;

    for (int kc = 0; kc < Ss / 64; ++kc) {
        const short* krow = QKV + ((size_t)(b * Ss + kc * 64 + srow)) * 3072 + 1024 + h * 64 + sdc;
        const short* vrow = krow + 1024;
#pragma unroll
        for (int j = 0; j < 2; ++j) {
            *(s16x8*)&Kl[srow][sdc + j * 8] = *(const s16x8*)(krow + j * 8);
            const s16x8 vv = *(const s16x8*)(vrow + j * 8);
#pragma unroll
            for (int t = 0; t < 8; ++t) Vt[sdc + j * 8 + t][srow] = vv[t];
        }
        __syncthreads();

        // QK^T
        f32x4 s[4];
#pragma unroll
        for (int kt = 0; kt < 4; ++kt) {
            f32x4 acc = {};
#pragma unroll
            for (int half = 0; half < 2; ++half) {
                const s16x8 bk = *(const s16x8*)&Kl[kt * 16 + lr][half * 32 + lg * 8];
                acc = __builtin_amdgcn_mfma_f32_16x16x32_bf16(qf[half], bk, acc, 0, 0, 0);
            }
            s[kt] = acc;
        }

        // scale + mask + row max
        float mt[4];
#pragma unroll
        for (int r = 0; r < 4; ++r) mt[r] = -INFINITY;
#pragma unroll
        for (int kt = 0; kt < 4; ++kt) {
            const float mv = mrow[kc * 64 + kt * 16 + lr];
#pragma unroll
            for (int r = 0; r < 4; ++r) {
                s[kt][r] = s[kt][r] * SCALEf + mv;
                mt[r] = fmaxf(mt[r], s[kt][r]);
            }
        }
#pragma unroll
        for (int o = 1; o <= 8; o <<= 1) {
#pragma unroll
            for (int r = 0; r < 4; ++r) mt[r] = fmaxf(mt[r], __shfl_xor(mt[r], o, 64));
        }

        // online softmax
        float corr[4], rs[4];
#pragma unroll
        for (int r = 0; r < 4; ++r) {
            const float mn = fmaxf(m_run[r], mt[r]);
            corr[r] = __expf(m_run[r] - mn);
            m_run[r] = mn;
            rs[r] = 0.0f;
        }
#pragma unroll
        for (int kt = 0; kt < 4; ++kt) {
#pragma unroll
            for (int r = 0; r < 4; ++r) {
                const float p = __expf(s[kt][r] - m_run[r]);
                rs[r] += p;
                Pl[wv][lg * 4 + r][kt * 16 + lr] = f2bs(p);
            }
        }
#pragma unroll
        for (int o = 1; o <= 8; o <<= 1) {
#pragma unroll
            for (int r = 0; r < 4; ++r) rs[r] += __shfl_xor(rs[r], o, 64);
        }
#pragma unroll
        for (int r = 0; r < 4; ++r) l_run[r] = l_run[r] * corr[r] + rs[r];
#pragma unroll
        for (int dt = 0; dt < 4; ++dt)
#pragma unroll
            for (int r = 0; r < 4; ++r) o_acc[dt][r] *= corr[r];

        // PV
#pragma unroll
        for (int kh = 0; kh < 2; ++kh) {
            const s16x8 pa = *(const s16x8*)&Pl[wv][lr][kh * 32 + lg * 8];
#pragma unroll
            for (int dt = 0; dt < 4; ++dt) {
                const s16x8 bv = *(const s16x8*)&Vt[dt * 16 + lr][kh * 32 + lg * 8];
                o_acc[dt] = __builtin_amdgcn_mfma_f32_16x16x32_bf16(pa, bv, o_acc[dt], 0, 0, 0);
            }
        }
        __syncthreads();
    }

#pragma unroll
    for (int r = 0; r < 4; ++r) {
        const float inv = 1.0f / l_run[r];
        short* orow = Oa + ((size_t)(b * Ss + q0 + lg * 4 + r)) * Dd + h * 64 + lr;
#pragma unroll
        for (int dt = 0; dt < 4; ++dt) orow[dt * 16] = f2bs(o_acc[dt][r] * inv);
    }
}

// ---------------------------------------------------------------------------
extern "C" void kernel_launch(void* const* d_in, const int* in_sizes, int n_in,
                              void* d_out, int out_size, void* d_ws, size_t ws_size,
                              hipStream_t stream) {
    const float* x    = (const float*)d_in[0];
    const float* mask = (const float*)d_in[1];
    const float* wq   = (const float*)d_in[2];
    const float* wk   = (const float*)d_in[3];
    const float* wv   = (const float*)d_in[4];
    const float* wo   = (const float*)d_in[5];
    const float* w1   = (const float*)d_in[6];
    const float* w2   = (const float*)d_in[7];
    const float* ln1g = (const float*)d_in[8];
    const float* ln1b = (const float*)d_in[9];
    const float* ln2g = (const float*)d_in[10];
    const float* ln2b = (const float*)d_in[11];
    float* out = (float*)d_out;

    char* p = (char*)d_ws;
    short* qkvw_t = (short*)p; p += (size_t)3072 * 1024 * 2;   // 6 MB
    short* wot    = (short*)p; p += (size_t)1024 * 1024 * 2;   // 2 MB
    short* w1t    = (short*)p; p += (size_t)4096 * 1024 * 2;   // 8 MB
    short* w2t    = (short*)p; p += (size_t)1024 * 4096 * 2;   // 8 MB
    short* y_bf   = (short*)p; p += (size_t)4096 * 1024 * 2;   // 8 MB
    short* qkv    = (short*)p; p += (size_t)4096 * 3072 * 2;   // 24 MB
    short* attn_b = (short*)p; p += (size_t)4096 * 1024 * 2;   // 8 MB
    short* y2_bf  = (short*)p; p += (size_t)4096 * 1024 * 2;   // 8 MB
    short* h_bf   = (short*)p; p += (size_t)4096 * 4096 * 2;   // 32 MB

    const int M = Bb * Ss;  // 4096

    // weight transpose+convert (Wt[n][k] = bf16(W[k][n]))
    transpose_w<<<dim3(16, 16), 256, 0, stream>>>(wq, qkvw_t,                      1024, 1024);
    transpose_w<<<dim3(16, 16), 256, 0, stream>>>(wk, qkvw_t + (size_t)1024 * 1024, 1024, 1024);
    transpose_w<<<dim3(16, 16), 256, 0, stream>>>(wv, qkvw_t + (size_t)2048 * 1024, 1024, 1024);
    transpose_w<<<dim3(16, 16), 256, 0, stream>>>(wo, wot, 1024, 1024);
    transpose_w<<<dim3(64, 16), 256, 0, stream>>>(w1, w1t, 1024, 4096);
    transpose_w<<<dim3(16, 64), 256, 0, stream>>>(w2, w2t, 4096, 1024);

    // LN1 -> bf16
    layernorm_bf16<<<M, 256, 0, stream>>>(x, ln1g, ln1b, y_bf);
    // fused QKV projection: [4096,1024] @ [1024,3072] -> bf16 [4096,3072]
    gemm_bf16<0><<<dim3(24, 32), 256, 0, stream>>>(y_bf, qkvw_t, nullptr, qkv, M, 3072, 1024);
    // flash attention
    attn_mfma<<<Bb * Hh * (Ss / 64), 256, 0, stream>>>(qkv, mask, attn_b);
    // out proj + residual -> fp32 d_out
    gemm_bf16<2><<<dim3(8, 32), 256, 0, stream>>>(attn_b, wot, x, out, M, 1024, 1024);
    // LN2 -> bf16
    layernorm_bf16<<<M, 256, 0, stream>>>(out, ln2g, ln2b, y2_bf);
    // FFN up + GELU -> bf16
    gemm_bf16<1><<<dim3(32, 32), 256, 0, stream>>>(y2_bf, w1t, nullptr, h_bf, M, 4096, 1024);
    // FFN down + residual -> fp32 d_out (in-place residual)
    gemm_bf16<2><<<dim3(8, 32), 256, 0, stream>>>(h_bf, w2t, out, out, M, 1024, 4096);
}

// Round 4
// 363.108 us; speedup vs baseline: 26.1504x; 1.0789x over previous
//
#include <hip/hip_runtime.h>
#include <hip/hip_bf16.h>
#include <math.h>

// Problem constants
#define Bb 2
#define Ss 2048
#define Dd 1024
#define Hh 16
#define FFf 4096
#define EPSf 1e-5f
#define SCALEf 0.03125f   // 1/sqrt(1024)

typedef short s16x8 __attribute__((ext_vector_type(8)));
typedef short s16x4 __attribute__((ext_vector_type(4)));
typedef float f32x4 __attribute__((ext_vector_type(4)));

// fp32 -> bf16 (RNE) raw bits
__device__ __forceinline__ short f2bs(float f) {
    union { float f; unsigned u; } v; v.f = f;
    const unsigned r = (v.u + 0x7FFFu + ((v.u >> 16) & 1u)) >> 16;
    return (short)r;
}
__device__ __forceinline__ float gelu_exact(float v) {
    return 0.5f * v * (1.0f + erff(v * 0.7071067811865475f));
}
// async global->LDS, 16B per lane; LDS dest is wave-uniform base + lane*16
__device__ __forceinline__ void gload16(const void* g, void* l) {
    __builtin_amdgcn_global_load_lds(
        (const __attribute__((address_space(1))) unsigned int*)g,
        (__attribute__((address_space(3))) unsigned int*)l, 16, 0, 0);
}

// ---------------------------------------------------------------------------
// Weight transpose + fp32->bf16: W[K][N] f32 -> Wt[N][K] bf16
// ---------------------------------------------------------------------------
__global__ __launch_bounds__(256) void transpose_w(const float* __restrict__ W,
                                                   short* __restrict__ Wt,
                                                   int K, int N) {
    __shared__ short T[64][65];
    const int tid = threadIdx.x;
    const int n0 = blockIdx.x * 64, k0 = blockIdx.y * 64;
    const int c = tid & 63, rg = tid >> 6;
#pragma unroll
    for (int j = 0; j < 16; ++j) {
        const int r = rg * 16 + j;
        T[r][c] = f2bs(W[(size_t)(k0 + r) * N + n0 + c]);
    }
    __syncthreads();
#pragma unroll
    for (int j = 0; j < 16; ++j) {
        const int r = rg * 16 + j;
        Wt[(size_t)(n0 + r) * K + k0 + c] = T[c][r];
    }
}

// ---------------------------------------------------------------------------
// V transpose: QKV[tok][3072] (V = cols 2048..3071, bf16) -> VT[b][h][d=64][s=2048]
// grid (32 = b*h, 16 = s/128), 256 thr. XOR-swizzled LDS tile.
// ---------------------------------------------------------------------------
__global__ __launch_bounds__(256) void vtranspose(const short* __restrict__ QKV,
                                                  short* __restrict__ VT) {
    __shared__ __align__(16) short T[64 * 144];
    const int t = threadIdx.x;
    const int bh = blockIdx.x;       // b*16 + h
    const int sc = blockIdx.y;       // s-chunk of 128
    const int b = bh >> 4, h = bh & 15;
#pragma unroll
    for (int i = 0; i < 4; ++i) {
        const int sl = i * 32 + (t >> 3);
        const int d0 = (t & 7) * 8;
        const s16x8 v = *(const s16x8*)&QKV[((size_t)(b * Ss + sc * 128 + sl)) * 3072 + 2048 + h * 64 + d0];
#pragma unroll
        for (int e = 0; e < 8; ++e) {
            const int d = d0 + e;
            T[(d * 144 + sl) ^ (((d >> 3) & 7) << 3)] = v[e];
        }
    }
    __syncthreads();
#pragma unroll
    for (int i = 0; i < 4; ++i) {
        const int d = i * 16 + (t >> 4);
        const int s0 = (t & 15) * 8;
        const s16x8 o = *(const s16x8*)&T[(d * 144 + s0) ^ (((d >> 3) & 7) << 3)];
        *(s16x8*)&VT[((size_t)(bh * 64 + d)) * 2048 + sc * 128 + s0] = o;
    }
}

// ---------------------------------------------------------------------------
// LayerNorm: one row per 256-thread block, fp32 in, bf16 out.
// ---------------------------------------------------------------------------
__global__ __launch_bounds__(256) void layernorm_bf16(const float* __restrict__ X,
                                                      const float* __restrict__ g,
                                                      const float* __restrict__ bta,
                                                      short* __restrict__ Y) {
    __shared__ float red[8];
    const int row = blockIdx.x;
    const int tid = threadIdx.x;
    const size_t base = (size_t)row * Dd + tid * 4;
    const float4 xv = *(const float4*)&X[base];
    float s  = xv.x + xv.y + xv.z + xv.w;
    float sq = xv.x * xv.x + xv.y * xv.y + xv.z * xv.z + xv.w * xv.w;
#pragma unroll
    for (int o = 32; o >= 1; o >>= 1) {
        s  += __shfl_xor(s, o, 64);
        sq += __shfl_xor(sq, o, 64);
    }
    const int lane = tid & 63, wv = tid >> 6;
    if (lane == 0) { red[wv] = s; red[4 + wv] = sq; }
    __syncthreads();
    const float tot  = red[0] + red[1] + red[2] + red[3];
    const float totq = red[4] + red[5] + red[6] + red[7];
    const float mu  = tot * (1.0f / Dd);
    const float var = totq * (1.0f / Dd) - mu * mu;
    const float inv = 1.0f / sqrtf(var + EPSf);
    const float4 gv = *(const float4*)&g[tid * 4];
    const float4 bv = *(const float4*)&bta[tid * 4];
    s16x4 o;
    o[0] = f2bs((xv.x - mu) * inv * gv.x + bv.x);
    o[1] = f2bs((xv.y - mu) * inv * gv.y + bv.y);
    o[2] = f2bs((xv.z - mu) * inv * gv.z + bv.z);
    o[3] = f2bs((xv.w - mu) * inv * gv.w + bv.w);
    *(s16x4*)&Y[base] = o;
}

// ---------------------------------------------------------------------------
// bf16 MFMA GEMM (m97 structure): C[M,N] = A[M,K] @ Bt[N,K]^T
// EPI: 0 = bf16 out, 1 = GELU + bf16 out, 2 = +R (fp32) -> fp32 out
// ---------------------------------------------------------------------------
template <int EPI>
__global__ __launch_bounds__(256) void gemm_bf16(const short* __restrict__ A,
                                                 const short* __restrict__ Bt,
                                                 const float* __restrict__ R,
                                                 void* __restrict__ Cout,
                                                 int M, int N, int K) {
    __shared__ short As[128 * 32];
    __shared__ short Bs[128 * 32];
    const int tid = threadIdx.x;
    const int w = tid >> 6, l = tid & 63;
    const int lr = l & 15, lg = l >> 4;
    const int wr = w >> 1, wc = w & 1;
    const int bx = blockIdx.x, by = blockIdx.y;

    const int srow = l >> 2;
    const int skb  = (l & 3) * 8;
    const size_t arow0 = (size_t)(by * 128 + w * 32);
    const size_t brow0 = (size_t)(bx * 128 + w * 32);

    f32x4 acc[4][4] = {};

    for (int k0 = 0; k0 < K; k0 += 32) {
        __syncthreads();
#pragma unroll
        for (int j = 0; j < 2; ++j) {
            gload16(A + (arow0 + j * 16 + srow) * K + k0 + skb,
                    &As[(w * 32 + j * 16) * 32]);
            gload16(Bt + (brow0 + j * 16 + srow) * K + k0 + skb,
                    &Bs[(w * 32 + j * 16) * 32]);
        }
        __syncthreads();
        s16x8 a[4], b[4];
#pragma unroll
        for (int m = 0; m < 4; ++m)
            a[m] = *(const s16x8*)&As[(wr * 64 + m * 16 + lr) * 32 + lg * 8];
#pragma unroll
        for (int n = 0; n < 4; ++n)
            b[n] = *(const s16x8*)&Bs[(wc * 64 + n * 16 + lr) * 32 + lg * 8];
#pragma unroll
        for (int m = 0; m < 4; ++m)
#pragma unroll
            for (int n = 0; n < 4; ++n)
                acc[m][n] = __builtin_amdgcn_mfma_f32_16x16x32_bf16(a[m], b[n], acc[m][n], 0, 0, 0);
    }

    const int row0 = by * 128 + wr * 64;
    const int col0 = bx * 128 + wc * 64;
#pragma unroll
    for (int m = 0; m < 4; ++m) {
#pragma unroll
        for (int r = 0; r < 4; ++r) {
            const int row = row0 + m * 16 + lg * 4 + r;
#pragma unroll
            for (int n = 0; n < 4; ++n) {
                const int col = col0 + n * 16 + lr;
                float v = acc[m][n][r];
                if (EPI == 1) v = gelu_exact(v);
                if (EPI == 2) {
                    float* C = (float*)Cout;
                    C[(size_t)row * N + col] = v + R[(size_t)row * N + col];
                } else {
                    ((short*)Cout)[(size_t)row * N + col] = f2bs(v);
                }
            }
        }
    }
}

// ---------------------------------------------------------------------------
// MFMA bf16 flash attention, swapped operands.
// Block = 4 waves = 64 q of one (b,h); KBLK=64, double-buffered K/V^T staging
// via global_load_lds + XOR source swizzle. S^T = mfma(K,Q): per-lane q=lane&15.
// PV: O^T = mfma(V^T, P). P via 4x ds_write_b64 per tile.
// ---------------------------------------------------------------------------
__global__ __launch_bounds__(256) void attn_mfma(const short* __restrict__ QKV,
                                                 const short* __restrict__ VT,
                                                 const float* __restrict__ mask,
                                                 short* __restrict__ Oa) {
    __shared__ __align__(16) short Kbuf[2][4096];   // [k=64][d=64] swizzled
    __shared__ __align__(16) short Vbuf[2][4096];   // [d=64][k=64] swizzled
    __shared__ __align__(16) short Pl[4][16][72];   // per-wave P[q][k]

    const int tid = threadIdx.x;
    const int wv = tid >> 6, lane = tid & 63;
    const int lg = lane >> 4, lr = lane & 15;
    const int bid = blockIdx.x;
    const int qt = bid & 31, h = (bid >> 5) & 15, b = bid >> 9;
    const int q0 = qt * 64 + wv * 16;

    // Q fragment (B-operand): q=lr, kappa(d) = hf*32 + lg*8 + i
    s16x8 qf[2];
    {
        const short* qsrc = QKV + ((size_t)(b * Ss + q0 + lr)) * 3072 + h * 64 + lg * 8;
        qf[0] = *(const s16x8*)(qsrc);
        qf[1] = *(const s16x8*)(qsrc + 32);
    }

    // staging: lane -> (row = base + lane>>3, slot = lane&7), source slot XOR'd
    const int srow8 = lane >> 3;
    const int scol  = ((lane & 7) ^ (srow8 & 7)) << 3;
    const short* kg = QKV + (size_t)b * Ss * 3072 + 1024 + h * 64 + scol;
    const short* vg = VT + ((size_t)(b * Hh + h) * 64) * 2048 + scol;

    f32x4 o_acc[4] = {};
    float m_run = -INFINITY, l_run = 0.0f;

    auto issue = [&](int bi, int kc) {
#pragma unroll
        for (int j = 0; j < 2; ++j) {
            const int r = wv * 16 + j * 8 + srow8;
            gload16(kg + ((size_t)(kc * 64 + r)) * 3072, &Kbuf[bi][(wv * 16 + j * 8) * 64]);
            gload16(vg + (size_t)r * 2048 + kc * 64,     &Vbuf[bi][(wv * 16 + j * 8) * 64]);
        }
    };

    issue(0, 0);
    int cur = 0;
    const float* mbase = mask + (size_t)b * Ss;

    for (int kc = 0; kc < Ss / 64; ++kc) {
        if (kc + 1 < Ss / 64) {
            issue(cur ^ 1, kc + 1);
            asm volatile("s_waitcnt vmcnt(4)" ::: "memory");
        } else {
            asm volatile("s_waitcnt vmcnt(0)" ::: "memory");
        }
        __builtin_amdgcn_sched_barrier(0);
        __builtin_amdgcn_s_barrier();

        // ---- QK^T (swapped): S^T[k = kt*16+lg*4+r][q = lr] ----
        f32x4 sa[4] = {};
        __builtin_amdgcn_s_setprio(1);
#pragma unroll
        for (int kt = 0; kt < 4; ++kt) {
#pragma unroll
            for (int hf = 0; hf < 2; ++hf) {
                const int r = kt * 16 + lr, c = hf * 32 + lg * 8;
                const s16x8 kfrag = *(const s16x8*)&Kbuf[cur][r * 64 + (((c >> 3) ^ (r & 7)) << 3)];
                sa[kt] = __builtin_amdgcn_mfma_f32_16x16x32_bf16(kfrag, qf[hf], sa[kt], 0, 0, 0);
            }
        }
        __builtin_amdgcn_s_setprio(0);

        // ---- scale + mask + max (per-lane q, 2-step reduce) ----
        float mt = -INFINITY;
#pragma unroll
        for (int kt = 0; kt < 4; ++kt) {
            const f32x4 mv = *(const f32x4*)&mbase[kc * 64 + kt * 16 + lg * 4];
#pragma unroll
            for (int r = 0; r < 4; ++r) {
                sa[kt][r] = sa[kt][r] * SCALEf + mv[r];
                mt = fmaxf(mt, sa[kt][r]);
            }
        }
        mt = fmaxf(mt, __shfl_xor(mt, 16, 64));
        mt = fmaxf(mt, __shfl_xor(mt, 32, 64));
        const float m_new = fmaxf(m_run, mt);
        const float corr = __expf(m_run - m_new);
        m_run = m_new;

        float rs = 0.0f;
#pragma unroll
        for (int kt = 0; kt < 4; ++kt) {
            const float p0 = __expf(sa[kt][0] - m_new);
            const float p1 = __expf(sa[kt][1] - m_new);
            const float p2 = __expf(sa[kt][2] - m_new);
            const float p3 = __expf(sa[kt][3] - m_new);
            rs += (p0 + p1) + (p2 + p3);
            s16x4 pw;
            pw[0] = f2bs(p0); pw[1] = f2bs(p1); pw[2] = f2bs(p2); pw[3] = f2bs(p3);
            *(s16x4*)&Pl[wv][lr][kt * 16 + lg * 4] = pw;
        }
        rs += __shfl_xor(rs, 16, 64);
        rs += __shfl_xor(rs, 32, 64);
        l_run = l_run * corr + rs;
#pragma unroll
        for (int dt = 0; dt < 4; ++dt)
#pragma unroll
            for (int r = 0; r < 4; ++r) o_acc[dt][r] *= corr;

        // ---- PV (swapped): O^T[d = dt*16+lg*4+r][q = lr] ----
        __builtin_amdgcn_s_setprio(1);
#pragma unroll
        for (int hf = 0; hf < 2; ++hf) {
            const s16x8 pfrag = *(const s16x8*)&Pl[wv][lr][hf * 32 + lg * 8];
#pragma unroll
            for (int dt = 0; dt < 4; ++dt) {
                const int r = dt * 16 + lr, c = hf * 32 + lg * 8;
                const s16x8 vfrag = *(const s16x8*)&Vbuf[cur][r * 64 + (((c >> 3) ^ (r & 7)) << 3)];
                o_acc[dt] = __builtin_amdgcn_mfma_f32_16x16x32_bf16(vfrag, pfrag, o_acc[dt], 0, 0, 0);
            }
        }
        __builtin_amdgcn_s_setprio(0);
        __builtin_amdgcn_s_barrier();
        cur ^= 1;
    }

    // ---- epilogue: per-lane q = q0+lr, d = dt*16 + lg*4 + r ----
    const float inv = 1.0f / l_run;
#pragma unroll
    for (int dt = 0; dt < 4; ++dt) {
        s16x4 ov;
#pragma unroll
        for (int r = 0; r < 4; ++r) ov[r] = f2bs(o_acc[dt][r] * inv);
        *(s16x4*)&Oa[((size_t)(b * Ss + q0 + lr)) * Dd + h * 64 + dt * 16 + lg * 4] = ov;
    }
}

// ---------------------------------------------------------------------------
extern "C" void kernel_launch(void* const* d_in, const int* in_sizes, int n_in,
                              void* d_out, int out_size, void* d_ws, size_t ws_size,
                              hipStream_t stream) {
    const float* x    = (const float*)d_in[0];
    const float* mask = (const float*)d_in[1];
    const float* wq   = (const float*)d_in[2];
    const float* wk   = (const float*)d_in[3];
    const float* wv   = (const float*)d_in[4];
    const float* wo   = (const float*)d_in[5];
    const float* w1   = (const float*)d_in[6];
    const float* w2   = (const float*)d_in[7];
    const float* ln1g = (const float*)d_in[8];
    const float* ln1b = (const float*)d_in[9];
    const float* ln2g = (const float*)d_in[10];
    const float* ln2b = (const float*)d_in[11];
    float* out = (float*)d_out;

    char* p = (char*)d_ws;
    short* qkvw_t = (short*)p; p += (size_t)3072 * 1024 * 2;   // 6 MB
    short* wot    = (short*)p; p += (size_t)1024 * 1024 * 2;   // 2 MB
    short* w1t    = (short*)p; p += (size_t)4096 * 1024 * 2;   // 8 MB
    short* w2t    = (short*)p; p += (size_t)1024 * 4096 * 2;   // 8 MB
    short* y_bf   = (short*)p; p += (size_t)4096 * 1024 * 2;   // 8 MB
    short* qkv    = (short*)p; p += (size_t)4096 * 3072 * 2;   // 24 MB
    short* attn_b = (short*)p; p += (size_t)4096 * 1024 * 2;   // 8 MB
    short* y2_bf  = (short*)p; p += (size_t)4096 * 1024 * 2;   // 8 MB
    short* h_bf   = (short*)p; p += (size_t)4096 * 4096 * 2;   // 32 MB
    short* vt     = h_bf;   // VT[b][h][64][2048] (8 MB) — dead before h_bf is written

    const int M = Bb * Ss;  // 4096

    transpose_w<<<dim3(16, 16), 256, 0, stream>>>(wq, qkvw_t,                       1024, 1024);
    transpose_w<<<dim3(16, 16), 256, 0, stream>>>(wk, qkvw_t + (size_t)1024 * 1024, 1024, 1024);
    transpose_w<<<dim3(16, 16), 256, 0, stream>>>(wv, qkvw_t + (size_t)2048 * 1024, 1024, 1024);
    transpose_w<<<dim3(16, 16), 256, 0, stream>>>(wo, wot, 1024, 1024);
    transpose_w<<<dim3(64, 16), 256, 0, stream>>>(w1, w1t, 1024, 4096);
    transpose_w<<<dim3(16, 64), 256, 0, stream>>>(w2, w2t, 4096, 1024);

    layernorm_bf16<<<M, 256, 0, stream>>>(x, ln1g, ln1b, y_bf);
    gemm_bf16<0><<<dim3(24, 32), 256, 0, stream>>>(y_bf, qkvw_t, nullptr, qkv, M, 3072, 1024);
    vtranspose<<<dim3(32, 16), 256, 0, stream>>>(qkv, vt);
    attn_mfma<<<Bb * Hh * (Ss / 64), 256, 0, stream>>>(qkv, vt, mask, attn_b);
    gemm_bf16<2><<<dim3(8, 32), 256, 0, stream>>>(attn_b, wot, x, out, M, 1024, 1024);
    layernorm_bf16<<<M, 256, 0, stream>>>(out, ln2g, ln2b, y2_bf);
    gemm_bf16<1><<<dim3(32, 32), 256, 0, stream>>>(y2_bf, w1t, nullptr, h_bf, M, 4096, 1024);
    gemm_bf16<2><<<dim3(8, 32), 256, 0, stream>>>(h_bf, w2t, out, out, M, 1024, 4096);
}

// Round 5
// 358.072 us; speedup vs baseline: 26.5181x; 1.0141x over previous
//
#include <hip/hip_runtime.h>
#include <hip/hip_bf16.h>
#include <math.h>

// Problem constants
#define Bb 2
#define Ss 2048
#define Dd 1024
#define Hh 16
#define FFf 4096
#define EPSf 1e-5f
#define SCALEf 0.03125f   // 1/sqrt(1024)
#define LOG2Ef 1.4426950408889634f
#define SCALE2f (SCALEf * LOG2Ef)
#define KSPLIT 2
#define NTILES ((Ss / KSPLIT) / 64)   // 16

typedef short s16x8 __attribute__((ext_vector_type(8)));
typedef short s16x4 __attribute__((ext_vector_type(4)));
typedef float f32x4 __attribute__((ext_vector_type(4)));
typedef float f32x16 __attribute__((ext_vector_type(16)));

// fp32 -> bf16 (RNE) raw bits
__device__ __forceinline__ short f2bs(float f) {
    union { float f; unsigned u; } v; v.f = f;
    const unsigned r = (v.u + 0x7FFFu + ((v.u >> 16) & 1u)) >> 16;
    return (short)r;
}
__device__ __forceinline__ float bs2f(short s) {
    union { unsigned u; float f; } v; v.u = ((unsigned)(unsigned short)s) << 16;
    return v.f;
}
__device__ __forceinline__ float gelu_exact(float v) {
    return 0.5f * v * (1.0f + erff(v * 0.7071067811865475f));
}
__device__ __forceinline__ void gload16(const void* g, void* l) {
    __builtin_amdgcn_global_load_lds(
        (const __attribute__((address_space(1))) unsigned int*)g,
        (__attribute__((address_space(3))) unsigned int*)l, 16, 0, 0);
}
__device__ __forceinline__ unsigned cvt_pk(float lo, float hi) {
    unsigned r;
    asm("v_cvt_pk_bf16_f32 %0, %1, %2" : "=v"(r) : "v"(lo), "v"(hi));
    return r;
}

// ---------------------------------------------------------------------------
// Fused prep: 6 weight transposes (fp32 -> bf16, W[K][N] -> Wt[N][K]) + mask*log2e
// ---------------------------------------------------------------------------
__global__ __launch_bounds__(256) void prep(const float* __restrict__ wq, const float* __restrict__ wk,
                                            const float* __restrict__ wv, const float* __restrict__ wo,
                                            const float* __restrict__ w1, const float* __restrict__ w2,
                                            const float* __restrict__ mask,
                                            short* __restrict__ qkvw_t, short* __restrict__ wot,
                                            short* __restrict__ w1t, short* __restrict__ w2t,
                                            float* __restrict__ msc) {
    const int blk = blockIdx.x;
    const int tid = threadIdx.x;
    if (blk >= 3072) {
#pragma unroll
        for (int j = 0; j < 16; ++j) msc[tid + j * 256] = mask[tid + j * 256] * LOG2Ef;
        return;
    }
    const float* W; short* Wt; int K, N, inner;
    if (blk < 1024) {
        const int which = blk >> 8; inner = blk & 255;
        K = 1024; N = 1024;
        W = (which == 0) ? wq : (which == 1) ? wk : (which == 2) ? wv : wo;
        Wt = (which < 3) ? qkvw_t + (size_t)which * 1024 * 1024 : wot;
    } else if (blk < 2048) {
        inner = blk - 1024; K = 1024; N = 4096; W = w1; Wt = w1t;
    } else {
        inner = blk - 2048; K = 4096; N = 1024; W = w2; Wt = w2t;
    }
    const int nbx = N / 64;
    const int bx = inner % nbx, by = inner / nbx;
    __shared__ short T[64][65];
    const int n0 = bx * 64, k0 = by * 64;
    const int c = tid & 63, rg = tid >> 6;
#pragma unroll
    for (int j = 0; j < 16; ++j) {
        const int r = rg * 16 + j;
        T[r][c] = f2bs(W[(size_t)(k0 + r) * N + n0 + c]);
    }
    __syncthreads();
#pragma unroll
    for (int j = 0; j < 16; ++j) {
        const int r = rg * 16 + j;
        Wt[(size_t)(n0 + r) * K + k0 + c] = T[c][r];
    }
}

// ---------------------------------------------------------------------------
// V transpose: QKV[tok][3072] (V cols 2048..3071) -> VT[b][h][d=64][s=2048]
// ---------------------------------------------------------------------------
__global__ __launch_bounds__(256) void vtranspose(const short* __restrict__ QKV,
                                                  short* __restrict__ VT) {
    __shared__ __align__(16) short T[64 * 144];
    const int t = threadIdx.x;
    const int bh = blockIdx.x;
    const int sc = blockIdx.y;
    const int b = bh >> 4, h = bh & 15;
#pragma unroll
    for (int i = 0; i < 4; ++i) {
        const int sl = i * 32 + (t >> 3);
        const int d0 = (t & 7) * 8;
        const s16x8 v = *(const s16x8*)&QKV[((size_t)(b * Ss + sc * 128 + sl)) * 3072 + 2048 + h * 64 + d0];
#pragma unroll
        for (int e = 0; e < 8; ++e) {
            const int d = d0 + e;
            T[(d * 144 + sl) ^ (((d >> 3) & 7) << 3)] = v[e];
        }
    }
    __syncthreads();
#pragma unroll
    for (int i = 0; i < 4; ++i) {
        const int d = i * 16 + (t >> 4);
        const int s0 = (t & 15) * 8;
        const s16x8 o = *(const s16x8*)&T[(d * 144 + s0) ^ (((d >> 3) & 7) << 3)];
        *(s16x8*)&VT[((size_t)(bh * 64 + d)) * 2048 + sc * 128 + s0] = o;
    }
}

// ---------------------------------------------------------------------------
// LayerNorm: fp32 in, bf16 out
// ---------------------------------------------------------------------------
__global__ __launch_bounds__(256) void layernorm_bf16(const float* __restrict__ X,
                                                      const float* __restrict__ g,
                                                      const float* __restrict__ bta,
                                                      short* __restrict__ Y) {
    __shared__ float red[8];
    const int row = blockIdx.x;
    const int tid = threadIdx.x;
    const size_t base = (size_t)row * Dd + tid * 4;
    const float4 xv = *(const float4*)&X[base];
    float s  = xv.x + xv.y + xv.z + xv.w;
    float sq = xv.x * xv.x + xv.y * xv.y + xv.z * xv.z + xv.w * xv.w;
#pragma unroll
    for (int o = 32; o >= 1; o >>= 1) {
        s  += __shfl_xor(s, o, 64);
        sq += __shfl_xor(sq, o, 64);
    }
    const int lane = tid & 63, wv = tid >> 6;
    if (lane == 0) { red[wv] = s; red[4 + wv] = sq; }
    __syncthreads();
    const float tot  = red[0] + red[1] + red[2] + red[3];
    const float totq = red[4] + red[5] + red[6] + red[7];
    const float mu  = tot * (1.0f / Dd);
    const float var = totq * (1.0f / Dd) - mu * mu;
    const float inv = 1.0f / sqrtf(var + EPSf);
    const float4 gv = *(const float4*)&g[tid * 4];
    const float4 bv = *(const float4*)&bta[tid * 4];
    s16x4 o;
    o[0] = f2bs((xv.x - mu) * inv * gv.x + bv.x);
    o[1] = f2bs((xv.y - mu) * inv * gv.y + bv.y);
    o[2] = f2bs((xv.z - mu) * inv * gv.z + bv.z);
    o[3] = f2bs((xv.w - mu) * inv * gv.w + bv.w);
    *(s16x4*)&Y[base] = o;
}

// ---------------------------------------------------------------------------
// bf16 MFMA GEMM (m97 structure): C[M,N] = A[M,K] @ Bt[N,K]^T
// ---------------------------------------------------------------------------
template <int EPI>
__global__ __launch_bounds__(256) void gemm_bf16(const short* __restrict__ A,
                                                 const short* __restrict__ Bt,
                                                 const float* __restrict__ R,
                                                 void* __restrict__ Cout,
                                                 int M, int N, int K) {
    __shared__ short As[128 * 32];
    __shared__ short Bs[128 * 32];
    const int tid = threadIdx.x;
    const int w = tid >> 6, l = tid & 63;
    const int lr = l & 15, lg = l >> 4;
    const int wr = w >> 1, wc = w & 1;
    const int bx = blockIdx.x, by = blockIdx.y;

    const int srow = l >> 2;
    const int skb  = (l & 3) * 8;
    const size_t arow0 = (size_t)(by * 128 + w * 32);
    const size_t brow0 = (size_t)(bx * 128 + w * 32);

    f32x4 acc[4][4] = {};

    for (int k0 = 0; k0 < K; k0 += 32) {
        __syncthreads();
#pragma unroll
        for (int j = 0; j < 2; ++j) {
            gload16(A + (arow0 + j * 16 + srow) * K + k0 + skb,
                    &As[(w * 32 + j * 16) * 32]);
            gload16(Bt + (brow0 + j * 16 + srow) * K + k0 + skb,
                    &Bs[(w * 32 + j * 16) * 32]);
        }
        __syncthreads();
        s16x8 a[4], b[4];
#pragma unroll
        for (int m = 0; m < 4; ++m)
            a[m] = *(const s16x8*)&As[(wr * 64 + m * 16 + lr) * 32 + lg * 8];
#pragma unroll
        for (int n = 0; n < 4; ++n)
            b[n] = *(const s16x8*)&Bs[(wc * 64 + n * 16 + lr) * 32 + lg * 8];
#pragma unroll
        for (int m = 0; m < 4; ++m)
#pragma unroll
            for (int n = 0; n < 4; ++n)
                acc[m][n] = __builtin_amdgcn_mfma_f32_16x16x32_bf16(a[m], b[n], acc[m][n], 0, 0, 0);
    }

    const int row0 = by * 128 + wr * 64;
    const int col0 = bx * 128 + wc * 64;
#pragma unroll
    for (int m = 0; m < 4; ++m) {
#pragma unroll
        for (int r = 0; r < 4; ++r) {
            const int row = row0 + m * 16 + lg * 4 + r;
#pragma unroll
            for (int n = 0; n < 4; ++n) {
                const int col = col0 + n * 16 + lr;
                float v = acc[m][n][r];
                if (EPI == 1) v = gelu_exact(v);
                if (EPI == 2) {
                    float* C = (float*)Cout;
                    C[(size_t)row * N + col] = v + R[(size_t)row * N + col];
                } else {
                    ((short*)Cout)[(size_t)row * N + col] = f2bs(v);
                }
            }
        }
    }
}

// ---------------------------------------------------------------------------
// Flash attention, 32x32x16 MFMA, swapped operands, in-register P, KSPLIT=2.
// Block = 2 waves x 32 q. K staged in LDS (dbuf, XOR src swizzle, gload_lds);
// V frags read direct from VT (L2). S^T = mfma(K,Q): q = lane&31 per-lane.
// P -> PV B-frags via 8 cvt_pk + 4 permlane32_swap. O^T = mfma(V^T, P).
// C/D layout (verified): col=lane&31, row=(reg&3)+8*(reg>>2)+4*(lane>>5).
// exp2-domain softmax, defer-max THR=8. Outputs unnormalized O + (m,l).
// ---------------------------------------------------------------------------
__global__ __launch_bounds__(128, 3) void attn_split(const short* __restrict__ QKV,
                                                     const short* __restrict__ VT,
                                                     const float* __restrict__ MSC,
                                                     short* __restrict__ Opart,
                                                     float2* __restrict__ ML) {
    __shared__ __align__(16) short Kbuf[2][64 * 64];

    const int tid = threadIdx.x;
    const int w = tid >> 6, l = tid & 63;
    const int col = l & 31;
    const int hi = l >> 5;

    const int bid = blockIdx.x;
    const int part = bid >> 10;
    const int inner = bid & 1023;
    const int qt = inner & 31, h = (inner >> 5) & 15, b = inner >> 9;
    const int q0 = qt * 64 + w * 32;
    const int k_base = part * (Ss / KSPLIT);

    // Q B-fragments: qf[dd][i] = Q[q0+col][h*64 + dd*16 + hi*8 + i]
    s16x8 qf[4];
    {
        const short* qsrc = QKV + ((size_t)(b * Ss + q0 + col)) * 3072 + h * 64 + hi * 8;
        qf[0] = *(const s16x8*)(qsrc);
        qf[1] = *(const s16x8*)(qsrc + 16);
        qf[2] = *(const s16x8*)(qsrc + 32);
        qf[3] = *(const s16x8*)(qsrc + 48);
    }

    // K staging: wave w instr j writes LDS rows [w*32+j*8, +8); lane -> row +l>>3, slot l&7
    const int sr_off = l >> 3;
    const int kslot = ((l & 7) ^ (sr_off & 7)) * 8;
    const short* kg = QKV + (size_t)(b * Ss) * 3072 + 1024 + h * 64 + kslot;
    const short* vgbase = VT + ((size_t)(b * Hh + h) * 64 + col) * 2048 + k_base + hi * 8;
    const float* mscb = MSC + (size_t)b * Ss + k_base;

    f32x16 o_acc[2] = {};
    float m_used = -1e30f, l_run = 0.0f;

    auto issue = [&](int bi, int t) {
#pragma unroll
        for (int j = 0; j < 4; ++j) {
            gload16(kg + ((size_t)(k_base + t * 64 + w * 32 + j * 8 + sr_off)) * 3072,
                    &Kbuf[bi][(w * 32 + j * 8) * 64]);
        }
    };

    issue(0, 0);
    int cur = 0;

    for (int i = 0; i < NTILES; ++i) {
        asm volatile("s_waitcnt vmcnt(0)" ::: "memory");
        __builtin_amdgcn_s_barrier();

        // V fragments for this tile (both subs), direct from global (L2)
        s16x8 vf[2][2][2];   // [sub][kk][dt]
#pragma unroll
        for (int sub = 0; sub < 2; ++sub)
#pragma unroll
            for (int kk = 0; kk < 2; ++kk)
#pragma unroll
                for (int dt = 0; dt < 2; ++dt)
                    vf[sub][kk][dt] = *(const s16x8*)(vgbase + (size_t)dt * 32 * 2048 +
                                                     i * 64 + sub * 32 + kk * 16);
        if (i + 1 < NTILES) issue(cur ^ 1, i + 1);

#pragma unroll
        for (int sub = 0; sub < 2; ++sub) {
            // ---- QK^T: S^T[32k][32q], k-local row = crow(reg,hi), col = q ----
            f32x16 sa = {};
#pragma unroll
            for (int dd = 0; dd < 4; ++dd) {
                const int r = sub * 32 + col;
                const s16x8 kf = *(const s16x8*)&Kbuf[cur][r * 64 + ((2 * dd + hi) ^ (r & 7)) * 8];
                sa = __builtin_amdgcn_mfma_f32_32x32x16_bf16(kf, qf[dd], sa, 0, 0, 0);
            }

            // ---- scale + mask (log2 domain) + row max ----
            float tmax = -1e30f;
#pragma unroll
            for (int c4 = 0; c4 < 4; ++c4) {
                const f32x4 mv = *(const f32x4*)&mscb[i * 64 + sub * 32 + 8 * c4 + 4 * hi];
#pragma unroll
                for (int rr = 0; rr < 4; ++rr) {
                    const int r = c4 * 4 + rr;
                    sa[r] = sa[r] * SCALE2f + mv[rr];
                    tmax = fmaxf(tmax, sa[r]);
                }
            }
            // cross-half max
            {
                unsigned a = __float_as_uint(tmax), bq = __float_as_uint(tmax);
                asm volatile("v_permlane32_swap_b32 %0, %1" : "+v"(a), "+v"(bq));
                tmax = fmaxf(tmax, __uint_as_float(hi ? a : bq));
            }
            // defer-max rescale
            if (__any(tmax > m_used + 8.0f)) {
                const float nm = fmaxf(m_used, tmax);
                const float corr = __builtin_amdgcn_exp2f(m_used - nm);
                m_used = nm;
                l_run *= corr;
#pragma unroll
                for (int dt = 0; dt < 2; ++dt)
#pragma unroll
                    for (int r = 0; r < 16; ++r) o_acc[dt][r] *= corr;
            }

            // ---- P = exp2(sa - m), pack to bf16, accumulate l ----
            unsigned wd[8];
#pragma unroll
            for (int m8 = 0; m8 < 8; ++m8) {
                const float p0 = __builtin_amdgcn_exp2f(sa[2 * m8]     - m_used);
                const float p1 = __builtin_amdgcn_exp2f(sa[2 * m8 + 1] - m_used);
                l_run += p0 + p1;
                wd[m8] = cvt_pk(p0, p1);
            }
            // ---- assemble PV B-frags via permlane32_swap ----
            unsigned f00 = wd[0], f02 = wd[2];
            asm volatile("v_permlane32_swap_b32 %0, %1" : "+v"(f00), "+v"(f02));
            unsigned f01 = wd[1], f03 = wd[3];
            asm volatile("v_permlane32_swap_b32 %0, %1" : "+v"(f01), "+v"(f03));
            unsigned f10 = wd[4], f12 = wd[6];
            asm volatile("v_permlane32_swap_b32 %0, %1" : "+v"(f10), "+v"(f12));
            unsigned f11 = wd[5], f13 = wd[7];
            asm volatile("v_permlane32_swap_b32 %0, %1" : "+v"(f11), "+v"(f13));
            union { unsigned u[4]; s16x8 v; } pf0, pf1;
            pf0.u[0] = f00; pf0.u[1] = f01; pf0.u[2] = f02; pf0.u[3] = f03;
            pf1.u[0] = f10; pf1.u[1] = f11; pf1.u[2] = f12; pf1.u[3] = f13;

            // ---- PV: O^T[d][q] += V^T @ P ----
            if (sub == 0) { asm volatile("s_waitcnt vmcnt(8)" ::: "memory"); }
            else          { asm volatile("s_waitcnt vmcnt(4)" ::: "memory"); }
#pragma unroll
            for (int dt = 0; dt < 2; ++dt) {
                o_acc[dt] = __builtin_amdgcn_mfma_f32_32x32x16_bf16(vf[sub][0][dt], pf0.v, o_acc[dt], 0, 0, 0);
                o_acc[dt] = __builtin_amdgcn_mfma_f32_32x32x16_bf16(vf[sub][1][dt], pf1.v, o_acc[dt], 0, 0, 0);
            }
        }
        cur ^= 1;
    }

    // ---- epilogue ----
    float l_tot;
    {
        unsigned a = __float_as_uint(l_run), bq = __float_as_uint(l_run);
        asm volatile("v_permlane32_swap_b32 %0, %1" : "+v"(a), "+v"(bq));
        l_tot = l_run + __uint_as_float(hi ? a : bq);
    }
    const size_t tok = (size_t)(b * Ss + q0 + col);
    if (hi == 0) {
        ML[(size_t)part * (Bb * Ss * Hh) + tok * Hh + h] = make_float2(m_used, l_tot);
    }
    short* obase = Opart + (size_t)part * (Bb * Ss) * Dd + tok * Dd + h * 64;
#pragma unroll
    for (int dt = 0; dt < 2; ++dt) {
#pragma unroll
        for (int c4 = 0; c4 < 4; ++c4) {
            s16x4 ov;
#pragma unroll
            for (int rr = 0; rr < 4; ++rr) ov[rr] = f2bs(o_acc[dt][c4 * 4 + rr]);
            *(s16x4*)&obase[dt * 32 + 8 * c4 + 4 * hi] = ov;
        }
    }
}

// ---------------------------------------------------------------------------
// KSPLIT combine: O = (o0*a0 + o1*a1) / (l0*a0 + l1*a1), a_i = exp2(m_i - M)
// ---------------------------------------------------------------------------
__global__ __launch_bounds__(256) void attn_combine(const short* __restrict__ Opart,
                                                    const float2* __restrict__ ML,
                                                    short* __restrict__ Oa) {
    const int tok = blockIdx.x;
    const int t = threadIdx.x;
    const int h = t >> 4;
    const int d = (t & 15) * 4;
    const float2 ml0 = ML[(size_t)tok * Hh + h];
    const float2 ml1 = ML[(size_t)(Bb * Ss * Hh) + (size_t)tok * Hh + h];
    const float M = fmaxf(ml0.x, ml1.x);
    const float a0 = __builtin_amdgcn_exp2f(ml0.x - M);
    const float a1 = __builtin_amdgcn_exp2f(ml1.x - M);
    const float inv = 1.0f / (ml0.y * a0 + ml1.y * a1);
    const size_t off = (size_t)tok * Dd + h * 64 + d;
    const s16x4 o0 = *(const s16x4*)&Opart[off];
    const s16x4 o1 = *(const s16x4*)&Opart[(size_t)(Bb * Ss) * Dd + off];
    s16x4 o;
#pragma unroll
    for (int r = 0; r < 4; ++r)
        o[r] = f2bs((bs2f(o0[r]) * a0 + bs2f(o1[r]) * a1) * inv);
    *(s16x4*)&Oa[off] = o;
}

// ---------------------------------------------------------------------------
extern "C" void kernel_launch(void* const* d_in, const int* in_sizes, int n_in,
                              void* d_out, int out_size, void* d_ws, size_t ws_size,
                              hipStream_t stream) {
    const float* x    = (const float*)d_in[0];
    const float* mask = (const float*)d_in[1];
    const float* wq   = (const float*)d_in[2];
    const float* wk   = (const float*)d_in[3];
    const float* wv   = (const float*)d_in[4];
    const float* wo   = (const float*)d_in[5];
    const float* w1   = (const float*)d_in[6];
    const float* w2   = (const float*)d_in[7];
    const float* ln1g = (const float*)d_in[8];
    const float* ln1b = (const float*)d_in[9];
    const float* ln2g = (const float*)d_in[10];
    const float* ln2b = (const float*)d_in[11];
    float* out = (float*)d_out;

    char* p = (char*)d_ws;
    short* qkvw_t = (short*)p; p += (size_t)3072 * 1024 * 2;   // 6 MB
    short* wot    = (short*)p; p += (size_t)1024 * 1024 * 2;   // 2 MB
    short* w1t    = (short*)p; p += (size_t)4096 * 1024 * 2;   // 8 MB
    short* w2t    = (short*)p; p += (size_t)1024 * 4096 * 2;   // 8 MB
    short* y_bf   = (short*)p; p += (size_t)4096 * 1024 * 2;   // 8 MB
    short* qkv    = (short*)p; p += (size_t)4096 * 3072 * 2;   // 24 MB
    short* attn_b = (short*)p; p += (size_t)4096 * 1024 * 2;   // 8 MB
    short* y2_bf  = (short*)p; p += (size_t)4096 * 1024 * 2;   // 8 MB
    char*  hregion = p;        p += (size_t)4096 * 4096 * 2;   // 32 MB (FFN mid, reused below)
    float* msc    = (float*)p; p += (size_t)Bb * Ss * 4;       // 16 KB

    // aliases inside hregion (all dead before FFN writes h_bf):
    short*  h_bf   = (short*)hregion;
    short*  vt     = (short*)hregion;                              // 8 MB
    short*  o_part = (short*)(hregion + (size_t)8 * 1024 * 1024);  // 16 MB
    float2* ml     = (float2*)(hregion + (size_t)24 * 1024 * 1024);// 1 MB

    const int M = Bb * Ss;  // 4096

    prep<<<3073, 256, 0, stream>>>(wq, wk, wv, wo, w1, w2, mask, qkvw_t, wot, w1t, w2t, msc);
    layernorm_bf16<<<M, 256, 0, stream>>>(x, ln1g, ln1b, y_bf);
    gemm_bf16<0><<<dim3(24, 32), 256, 0, stream>>>(y_bf, qkvw_t, nullptr, qkv, M, 3072, 1024);
    vtranspose<<<dim3(32, 16), 256, 0, stream>>>(qkv, vt);
    attn_split<<<KSPLIT * 1024, 128, 0, stream>>>(qkv, vt, msc, o_part, ml);
    attn_combine<<<M, 256, 0, stream>>>(o_part, ml, attn_b);
    gemm_bf16<2><<<dim3(8, 32), 256, 0, stream>>>(attn_b, wot, x, out, M, 1024, 1024);
    layernorm_bf16<<<M, 256, 0, stream>>>(out, ln2g, ln2b, y2_bf);
    gemm_bf16<1><<<dim3(32, 32), 256, 0, stream>>>(y2_bf, w1t, nullptr, h_bf, M, 4096, 1024);
    gemm_bf16<2><<<dim3(8, 32), 256, 0, stream>>>(h_bf, w2t, out, out, M, 1024, 4096);
}

// Round 6
// 327.670 us; speedup vs baseline: 28.9786x; 1.0928x over previous
//
#include <hip/hip_runtime.h>
#include <hip/hip_bf16.h>
#include <math.h>

// Problem constants
#define Bb 2
#define Ss 2048
#define Dd 1024
#define Hh 16
#define FFf 4096
#define EPSf 1e-5f
#define SCALEf 0.03125f   // 1/sqrt(1024)
#define LOG2Ef 1.4426950408889634f
#define SCALE2f (SCALEf * LOG2Ef)
#define KSPLIT 4
#define NTILES ((Ss / KSPLIT) / 64)   // 8

typedef short s16x8 __attribute__((ext_vector_type(8)));
typedef short s16x4 __attribute__((ext_vector_type(4)));
typedef float f32x4 __attribute__((ext_vector_type(4)));
typedef float f32x16 __attribute__((ext_vector_type(16)));

// fp32 -> bf16 (RNE) raw bits
__device__ __forceinline__ short f2bs(float f) {
    union { float f; unsigned u; } v; v.f = f;
    const unsigned r = (v.u + 0x7FFFu + ((v.u >> 16) & 1u)) >> 16;
    return (short)r;
}
__device__ __forceinline__ float bs2f(short s) {
    union { unsigned u; float f; } v; v.u = ((unsigned)(unsigned short)s) << 16;
    return v.f;
}
__device__ __forceinline__ float gelu_exact(float v) {
    return 0.5f * v * (1.0f + erff(v * 0.7071067811865475f));
}
__device__ __forceinline__ void gload16(const void* g, void* l) {
    __builtin_amdgcn_global_load_lds(
        (const __attribute__((address_space(1))) unsigned int*)g,
        (__attribute__((address_space(3))) unsigned int*)l, 16, 0, 0);
}
__device__ __forceinline__ unsigned cvt_pk(float lo, float hi) {
    unsigned r;
    asm("v_cvt_pk_bf16_f32 %0, %1, %2" : "=v"(r) : "v"(lo), "v"(hi));
    return r;
}

// ---------------------------------------------------------------------------
// Fused prep: 6 weight transposes (fp32 -> bf16, W[K][N] -> Wt[N][K]) + mask*log2e
// ---------------------------------------------------------------------------
__global__ __launch_bounds__(256) void prep(const float* __restrict__ wq, const float* __restrict__ wk,
                                            const float* __restrict__ wv, const float* __restrict__ wo,
                                            const float* __restrict__ w1, const float* __restrict__ w2,
                                            const float* __restrict__ mask,
                                            short* __restrict__ qkvw_t, short* __restrict__ wot,
                                            short* __restrict__ w1t, short* __restrict__ w2t,
                                            float* __restrict__ msc) {
    const int blk = blockIdx.x;
    const int tid = threadIdx.x;
    if (blk >= 3072) {
#pragma unroll
        for (int j = 0; j < 16; ++j) msc[tid + j * 256] = mask[tid + j * 256] * LOG2Ef;
        return;
    }
    const float* W; short* Wt; int K, N, inner;
    if (blk < 1024) {
        const int which = blk >> 8; inner = blk & 255;
        K = 1024; N = 1024;
        W = (which == 0) ? wq : (which == 1) ? wk : (which == 2) ? wv : wo;
        Wt = (which < 3) ? qkvw_t + (size_t)which * 1024 * 1024 : wot;
    } else if (blk < 2048) {
        inner = blk - 1024; K = 1024; N = 4096; W = w1; Wt = w1t;
    } else {
        inner = blk - 2048; K = 4096; N = 1024; W = w2; Wt = w2t;
    }
    const int nbx = N / 64;
    const int bx = inner % nbx, by = inner / nbx;
    __shared__ short T[64][65];
    const int n0 = bx * 64, k0 = by * 64;
    const int c = tid & 63, rg = tid >> 6;
#pragma unroll
    for (int j = 0; j < 16; ++j) {
        const int r = rg * 16 + j;
        T[r][c] = f2bs(W[(size_t)(k0 + r) * N + n0 + c]);
    }
    __syncthreads();
#pragma unroll
    for (int j = 0; j < 16; ++j) {
        const int r = rg * 16 + j;
        Wt[(size_t)(n0 + r) * K + k0 + c] = T[c][r];
    }
}

// ---------------------------------------------------------------------------
// V transpose: QKV[tok][3072] (V cols 2048..3071) -> VT[b][h][d=64][s=2048]
// ---------------------------------------------------------------------------
__global__ __launch_bounds__(256) void vtranspose(const short* __restrict__ QKV,
                                                  short* __restrict__ VT) {
    __shared__ __align__(16) short T[64 * 144];
    const int t = threadIdx.x;
    const int bh = blockIdx.x;
    const int sc = blockIdx.y;
    const int b = bh >> 4, h = bh & 15;
#pragma unroll
    for (int i = 0; i < 4; ++i) {
        const int sl = i * 32 + (t >> 3);
        const int d0 = (t & 7) * 8;
        const s16x8 v = *(const s16x8*)&QKV[((size_t)(b * Ss + sc * 128 + sl)) * 3072 + 2048 + h * 64 + d0];
#pragma unroll
        for (int e = 0; e < 8; ++e) {
            const int d = d0 + e;
            T[(d * 144 + sl) ^ (((d >> 3) & 7) << 3)] = v[e];
        }
    }
    __syncthreads();
#pragma unroll
    for (int i = 0; i < 4; ++i) {
        const int d = i * 16 + (t >> 4);
        const int s0 = (t & 15) * 8;
        const s16x8 o = *(const s16x8*)&T[(d * 144 + s0) ^ (((d >> 3) & 7) << 3)];
        *(s16x8*)&VT[((size_t)(bh * 64 + d)) * 2048 + sc * 128 + s0] = o;
    }
}

// ---------------------------------------------------------------------------
// LayerNorm: fp32 in, bf16 out
// ---------------------------------------------------------------------------
__global__ __launch_bounds__(256) void layernorm_bf16(const float* __restrict__ X,
                                                      const float* __restrict__ g,
                                                      const float* __restrict__ bta,
                                                      short* __restrict__ Y) {
    __shared__ float red[8];
    const int row = blockIdx.x;
    const int tid = threadIdx.x;
    const size_t base = (size_t)row * Dd + tid * 4;
    const float4 xv = *(const float4*)&X[base];
    float s  = xv.x + xv.y + xv.z + xv.w;
    float sq = xv.x * xv.x + xv.y * xv.y + xv.z * xv.z + xv.w * xv.w;
#pragma unroll
    for (int o = 32; o >= 1; o >>= 1) {
        s  += __shfl_xor(s, o, 64);
        sq += __shfl_xor(sq, o, 64);
    }
    const int lane = tid & 63, wv = tid >> 6;
    if (lane == 0) { red[wv] = s; red[4 + wv] = sq; }
    __syncthreads();
    const float tot  = red[0] + red[1] + red[2] + red[3];
    const float totq = red[4] + red[5] + red[6] + red[7];
    const float mu  = tot * (1.0f / Dd);
    const float var = totq * (1.0f / Dd) - mu * mu;
    const float inv = 1.0f / sqrtf(var + EPSf);
    const float4 gv = *(const float4*)&g[tid * 4];
    const float4 bv = *(const float4*)&bta[tid * 4];
    s16x4 o;
    o[0] = f2bs((xv.x - mu) * inv * gv.x + bv.x);
    o[1] = f2bs((xv.y - mu) * inv * gv.y + bv.y);
    o[2] = f2bs((xv.z - mu) * inv * gv.z + bv.z);
    o[3] = f2bs((xv.w - mu) * inv * gv.w + bv.w);
    *(s16x4*)&Y[base] = o;
}

// ---------------------------------------------------------------------------
// bf16 MFMA GEMM (m97 structure): C[M,N] = A[M,K] @ Bt[N,K]^T
// ---------------------------------------------------------------------------
template <int EPI>
__global__ __launch_bounds__(256) void gemm_bf16(const short* __restrict__ A,
                                                 const short* __restrict__ Bt,
                                                 const float* __restrict__ R,
                                                 void* __restrict__ Cout,
                                                 int M, int N, int K) {
    __shared__ short As[128 * 32];
    __shared__ short Bs[128 * 32];
    const int tid = threadIdx.x;
    const int w = tid >> 6, l = tid & 63;
    const int lr = l & 15, lg = l >> 4;
    const int wr = w >> 1, wc = w & 1;
    const int bx = blockIdx.x, by = blockIdx.y;

    const int srow = l >> 2;
    const int skb  = (l & 3) * 8;
    const size_t arow0 = (size_t)(by * 128 + w * 32);
    const size_t brow0 = (size_t)(bx * 128 + w * 32);

    f32x4 acc[4][4] = {};

    for (int k0 = 0; k0 < K; k0 += 32) {
        __syncthreads();
#pragma unroll
        for (int j = 0; j < 2; ++j) {
            gload16(A + (arow0 + j * 16 + srow) * K + k0 + skb,
                    &As[(w * 32 + j * 16) * 32]);
            gload16(Bt + (brow0 + j * 16 + srow) * K + k0 + skb,
                    &Bs[(w * 32 + j * 16) * 32]);
        }
        __syncthreads();
        s16x8 a[4], b[4];
#pragma unroll
        for (int m = 0; m < 4; ++m)
            a[m] = *(const s16x8*)&As[(wr * 64 + m * 16 + lr) * 32 + lg * 8];
#pragma unroll
        for (int n = 0; n < 4; ++n)
            b[n] = *(const s16x8*)&Bs[(wc * 64 + n * 16 + lr) * 32 + lg * 8];
#pragma unroll
        for (int m = 0; m < 4; ++m)
#pragma unroll
            for (int n = 0; n < 4; ++n)
                acc[m][n] = __builtin_amdgcn_mfma_f32_16x16x32_bf16(a[m], b[n], acc[m][n], 0, 0, 0);
    }

    const int row0 = by * 128 + wr * 64;
    const int col0 = bx * 128 + wc * 64;
#pragma unroll
    for (int m = 0; m < 4; ++m) {
#pragma unroll
        for (int r = 0; r < 4; ++r) {
            const int row = row0 + m * 16 + lg * 4 + r;
#pragma unroll
            for (int n = 0; n < 4; ++n) {
                const int col = col0 + n * 16 + lr;
                float v = acc[m][n][r];
                if (EPI == 1) v = gelu_exact(v);
                if (EPI == 2) {
                    float* C = (float*)Cout;
                    C[(size_t)row * N + col] = v + R[(size_t)row * N + col];
                } else {
                    ((short*)Cout)[(size_t)row * N + col] = f2bs(v);
                }
            }
        }
    }
}

// ---------------------------------------------------------------------------
// Flash attention v2: 32x32x16 MFMA, swapped operands, in-register P.
// Block = 4 waves x 32 q = 128 q. KSPLIT=4 (8 k-tiles of 64 per part).
// K AND V staged in LDS (dbuf, gload_lds w16, XOR source swizzle, coalesced).
// 2-phase schedule: {vmcnt(0); barrier; STAGE(next); compute(cur)} — prefetch
// waited one full iteration after issue. One barrier per tile.
// C/D layout: col=lane&31, row=(reg&3)+8*(reg>>2)+4*(lane>>5).
// ---------------------------------------------------------------------------
__global__ __launch_bounds__(256) void attn_split(const short* __restrict__ QKV,
                                                  const short* __restrict__ VT,
                                                  const float* __restrict__ MSC,
                                                  short* __restrict__ Opart,
                                                  float2* __restrict__ ML) {
    __shared__ __align__(16) short Kbuf[2][64 * 64];
    __shared__ __align__(16) short Vbuf[2][64 * 64];

    const int tid = threadIdx.x;
    const int w = tid >> 6, l = tid & 63;
    const int col = l & 31;
    const int hi = l >> 5;

    const int bid = blockIdx.x;
    const int part = bid >> 9;            // 0..3
    const int inner = bid & 511;
    const int qt = inner & 15, h = (inner >> 4) & 15, b = inner >> 8;
    const int q0 = qt * 128 + w * 32;
    const int k_base = part * (Ss / KSPLIT);

    // Q B-fragments: qf[dd][i] = Q[q0+col][h*64 + dd*16 + hi*8 + i]
    s16x8 qf[4];
    {
        const short* qsrc = QKV + ((size_t)(b * Ss + q0 + col)) * 3072 + h * 64 + hi * 8;
        qf[0] = *(const s16x8*)(qsrc);
        qf[1] = *(const s16x8*)(qsrc + 16);
        qf[2] = *(const s16x8*)(qsrc + 32);
        qf[3] = *(const s16x8*)(qsrc + 48);
    }

    // staging: wave w stages rows w*16 .. w*16+15 of the 64-row tile.
    // lane -> (row += l>>3, 16B slot (l&7) XOR'd with row&7) -> linear LDS dest.
    const int sr   = l >> 3;                       // 0..7
    const int slot = ((l & 7) ^ (sr & 7)) * 8;     // swizzled 8-short slot
    const short* kg = QKV + (size_t)(b * Ss) * 3072 + 1024 + h * 64 + (size_t)sr * 3072 + slot;
    const short* vg = VT + ((size_t)(b * Hh + h) * 64 + sr) * 2048 + k_base + slot;
    const float* mscb = MSC + (size_t)b * Ss + k_base;

    f32x16 o_acc[2] = {};
    float m_used = -1e30f, l_run = 0.0f;

    auto STAGE = [&](int bi, int t) {
#pragma unroll
        for (int j = 0; j < 2; ++j) {
            const int r0 = w * 16 + j * 8;
            gload16(kg + (size_t)(k_base + t * 64 + r0) * 3072, &Kbuf[bi][r0 * 64]);
            gload16(vg + (size_t)r0 * 2048 + t * 64,             &Vbuf[bi][r0 * 64]);
        }
    };

    STAGE(0, 0);
    int cur = 0;

    for (int i = 0; i < NTILES; ++i) {
        asm volatile("s_waitcnt vmcnt(0)" ::: "memory");
        __builtin_amdgcn_s_barrier();
        if (i + 1 < NTILES) STAGE(cur ^ 1, i + 1);

#pragma unroll
        for (int sub = 0; sub < 2; ++sub) {
            // ---- QK^T: S^T[32k][32q] ----
            f32x16 sa = {};
            const int rk = sub * 32 + col;
#pragma unroll
            for (int dd = 0; dd < 4; ++dd) {
                const s16x8 kf = *(const s16x8*)&Kbuf[cur][rk * 64 + ((2 * dd + hi) ^ (rk & 7)) * 8];
                sa = __builtin_amdgcn_mfma_f32_32x32x16_bf16(kf, qf[dd], sa, 0, 0, 0);
            }

            // ---- scale + mask (log2 domain) ----
#pragma unroll
            for (int c4 = 0; c4 < 4; ++c4) {
                const f32x4 mv = *(const f32x4*)&mscb[i * 64 + sub * 32 + 8 * c4 + 4 * hi];
#pragma unroll
                for (int rr = 0; rr < 4; ++rr) sa[c4 * 4 + rr] = sa[c4 * 4 + rr] * SCALE2f + mv[rr];
            }
            // ---- row max (tree) ----
            float t8[8], t4[4];
#pragma unroll
            for (int r = 0; r < 8; ++r) t8[r] = fmaxf(sa[2 * r], sa[2 * r + 1]);
#pragma unroll
            for (int r = 0; r < 4; ++r) t4[r] = fmaxf(t8[2 * r], t8[2 * r + 1]);
            float tmax = fmaxf(fmaxf(t4[0], t4[1]), fmaxf(t4[2], t4[3]));
            {
                unsigned a = __float_as_uint(tmax), bq = __float_as_uint(tmax);
                asm volatile("v_permlane32_swap_b32 %0, %1" : "+v"(a), "+v"(bq));
                tmax = fmaxf(tmax, __uint_as_float(hi ? a : bq));
            }
            // defer-max rescale (THR=8 in log2 domain)
            if (__any(tmax > m_used + 8.0f)) {
                const float nm = fmaxf(m_used, tmax);
                const float corr = __builtin_amdgcn_exp2f(m_used - nm);
                m_used = nm;
                l_run *= corr;
#pragma unroll
                for (int dt = 0; dt < 2; ++dt)
#pragma unroll
                    for (int r = 0; r < 16; ++r) o_acc[dt][r] *= corr;
            }

            // ---- P = exp2(sa - m), pack bf16, accumulate l (tree) ----
            unsigned wd[8];
            float s8[8];
#pragma unroll
            for (int m8 = 0; m8 < 8; ++m8) {
                const float p0 = __builtin_amdgcn_exp2f(sa[2 * m8]     - m_used);
                const float p1 = __builtin_amdgcn_exp2f(sa[2 * m8 + 1] - m_used);
                s8[m8] = p0 + p1;
                wd[m8] = cvt_pk(p0, p1);
            }
            float s4[4];
#pragma unroll
            for (int r = 0; r < 4; ++r) s4[r] = s8[2 * r] + s8[2 * r + 1];
            l_run += (s4[0] + s4[1]) + (s4[2] + s4[3]);

            // ---- assemble PV B-frags via permlane32_swap (verbatim R4 algebra) ----
            unsigned f00 = wd[0], f02 = wd[2];
            asm volatile("v_permlane32_swap_b32 %0, %1" : "+v"(f00), "+v"(f02));
            unsigned f01 = wd[1], f03 = wd[3];
            asm volatile("v_permlane32_swap_b32 %0, %1" : "+v"(f01), "+v"(f03));
            unsigned f10 = wd[4], f12 = wd[6];
            asm volatile("v_permlane32_swap_b32 %0, %1" : "+v"(f10), "+v"(f12));
            unsigned f11 = wd[5], f13 = wd[7];
            asm volatile("v_permlane32_swap_b32 %0, %1" : "+v"(f11), "+v"(f13));
            union { unsigned u[4]; s16x8 v; } pf0, pf1;
            pf0.u[0] = f00; pf0.u[1] = f01; pf0.u[2] = f02; pf0.u[3] = f03;
            pf1.u[0] = f10; pf1.u[1] = f11; pf1.u[2] = f12; pf1.u[3] = f13;

            // ---- PV: O^T[d][q] += V^T @ P (V frags from LDS, swizzled) ----
#pragma unroll
            for (int dt = 0; dt < 2; ++dt) {
                const int rv = dt * 32 + col;
                const s16x8 v0 = *(const s16x8*)&Vbuf[cur][rv * 64 + ((sub * 4 + 0 + hi) ^ (rv & 7)) * 8];
                const s16x8 v1 = *(const s16x8*)&Vbuf[cur][rv * 64 + ((sub * 4 + 2 + hi) ^ (rv & 7)) * 8];
                o_acc[dt] = __builtin_amdgcn_mfma_f32_32x32x16_bf16(v0, pf0.v, o_acc[dt], 0, 0, 0);
                o_acc[dt] = __builtin_amdgcn_mfma_f32_32x32x16_bf16(v1, pf1.v, o_acc[dt], 0, 0, 0);
            }
        }
        cur ^= 1;
    }

    // ---- epilogue ----
    float l_tot;
    {
        unsigned a = __float_as_uint(l_run), bq = __float_as_uint(l_run);
        asm volatile("v_permlane32_swap_b32 %0, %1" : "+v"(a), "+v"(bq));
        l_tot = l_run + __uint_as_float(hi ? a : bq);
    }
    const size_t tok = (size_t)(b * Ss + q0 + col);
    if (hi == 0) {
        ML[(size_t)part * (Bb * Ss * Hh) + tok * Hh + h] = make_float2(m_used, l_tot);
    }
    short* obase = Opart + (size_t)part * (Bb * Ss) * Dd + tok * Dd + h * 64;
#pragma unroll
    for (int dt = 0; dt < 2; ++dt) {
#pragma unroll
        for (int c4 = 0; c4 < 4; ++c4) {
            s16x4 ov;
#pragma unroll
            for (int rr = 0; rr < 4; ++rr) ov[rr] = f2bs(o_acc[dt][c4 * 4 + rr]);
            *(s16x4*)&obase[dt * 32 + 8 * c4 + 4 * hi] = ov;
        }
    }
}

// ---------------------------------------------------------------------------
// KSPLIT combine: O = sum_i o_i*a_i / sum_i l_i*a_i, a_i = exp2(m_i - M)
// ---------------------------------------------------------------------------
__global__ __launch_bounds__(256) void attn_combine(const short* __restrict__ Opart,
                                                    const float2* __restrict__ ML,
                                                    short* __restrict__ Oa) {
    const int tok = blockIdx.x;
    const int t = threadIdx.x;
    const int h = t >> 4;
    const int d = (t & 15) * 4;
    float2 ml[KSPLIT];
    float M = -1e30f;
#pragma unroll
    for (int p = 0; p < KSPLIT; ++p) {
        ml[p] = ML[(size_t)p * (Bb * Ss * Hh) + (size_t)tok * Hh + h];
        M = fmaxf(M, ml[p].x);
    }
    float a[KSPLIT], denom = 0.0f;
#pragma unroll
    for (int p = 0; p < KSPLIT; ++p) {
        a[p] = __builtin_amdgcn_exp2f(ml[p].x - M);
        denom += ml[p].y * a[p];
    }
    const float inv = 1.0f / denom;
    const size_t off = (size_t)tok * Dd + h * 64 + d;
    float acc[4] = {};
#pragma unroll
    for (int p = 0; p < KSPLIT; ++p) {
        const s16x4 o4 = *(const s16x4*)&Opart[(size_t)p * (Bb * Ss) * Dd + off];
#pragma unroll
        for (int r = 0; r < 4; ++r) acc[r] += bs2f(o4[r]) * a[p];
    }
    s16x4 o;
#pragma unroll
    for (int r = 0; r < 4; ++r) o[r] = f2bs(acc[r] * inv);
    *(s16x4*)&Oa[off] = o;
}

// ---------------------------------------------------------------------------
extern "C" void kernel_launch(void* const* d_in, const int* in_sizes, int n_in,
                              void* d_out, int out_size, void* d_ws, size_t ws_size,
                              hipStream_t stream) {
    const float* x    = (const float*)d_in[0];
    const float* mask = (const float*)d_in[1];
    const float* wq   = (const float*)d_in[2];
    const float* wk   = (const float*)d_in[3];
    const float* wv   = (const float*)d_in[4];
    const float* wo   = (const float*)d_in[5];
    const float* w1   = (const float*)d_in[6];
    const float* w2   = (const float*)d_in[7];
    const float* ln1g = (const float*)d_in[8];
    const float* ln1b = (const float*)d_in[9];
    const float* ln2g = (const float*)d_in[10];
    const float* ln2b = (const float*)d_in[11];
    float* out = (float*)d_out;

    char* p = (char*)d_ws;
    short* qkvw_t = (short*)p; p += (size_t)3072 * 1024 * 2;   // 6 MB
    short* wot    = (short*)p; p += (size_t)1024 * 1024 * 2;   // 2 MB
    short* w1t    = (short*)p; p += (size_t)4096 * 1024 * 2;   // 8 MB
    short* w2t    = (short*)p; p += (size_t)1024 * 4096 * 2;   // 8 MB
    short* y_bf   = (short*)p; p += (size_t)4096 * 1024 * 2;   // 8 MB
    short* qkv    = (short*)p; p += (size_t)4096 * 3072 * 2;   // 24 MB
    short* attn_b = (short*)p; p += (size_t)4096 * 1024 * 2;   // 8 MB
    short* y2_bf  = (short*)p; p += (size_t)4096 * 1024 * 2;   // 8 MB
    char*  hregion = p;        p += (size_t)4096 * 4096 * 2;   // 32 MB (FFN mid, reused below)
    float* msc    = (float*)p; p += (size_t)Bb * Ss * 4;       // 16 KB

    // aliases (lifetime-disjoint):
    short*  h_bf   = (short*)hregion;           // FFN mid (last use)
    short*  o_part = (short*)hregion;           // KSPLIT x 8 MB = 32 MB (dead before FFN)
    short*  vt     = y_bf;                      // VT 8 MB (y_bf dead after QKV GEMM)
    float2* ml     = (float2*)qkvw_t;           // 2 MB (qkvw_t dead after QKV GEMM)

    const int M = Bb * Ss;  // 4096

    prep<<<3073, 256, 0, stream>>>(wq, wk, wv, wo, w1, w2, mask, qkvw_t, wot, w1t, w2t, msc);
    layernorm_bf16<<<M, 256, 0, stream>>>(x, ln1g, ln1b, y_bf);
    gemm_bf16<0><<<dim3(24, 32), 256, 0, stream>>>(y_bf, qkvw_t, nullptr, qkv, M, 3072, 1024);
    vtranspose<<<dim3(32, 16), 256, 0, stream>>>(qkv, vt);
    attn_split<<<KSPLIT * 512, 256, 0, stream>>>(qkv, vt, msc, o_part, ml);
    attn_combine<<<M, 256, 0, stream>>>(o_part, ml, attn_b);
    gemm_bf16<2><<<dim3(8, 32), 256, 0, stream>>>(attn_b, wot, x, out, M, 1024, 1024);
    layernorm_bf16<<<M, 256, 0, stream>>>(out, ln2g, ln2b, y2_bf);
    gemm_bf16<1><<<dim3(32, 32), 256, 0, stream>>>(y2_bf, w1t, nullptr, h_bf, M, 4096, 1024);
    gemm_bf16<2><<<dim3(8, 32), 256, 0, stream>>>(h_bf, w2t, out, out, M, 1024, 4096);
}

// Round 7
// 284.350 us; speedup vs baseline: 33.3934x; 1.1523x over previous
//
#include <hip/hip_runtime.h>
#include <hip/hip_bf16.h>
#include <math.h>

// Problem constants
#define Bb 2
#define Ss 2048
#define Dd 1024
#define Hh 16
#define FFf 4096
#define EPSf 1e-5f
#define SCALEf 0.03125f   // 1/sqrt(1024)
#define LOG2Ef 1.4426950408889634f
#define SCALE2f (SCALEf * LOG2Ef)
#define KSPLIT 4
#define NTILES ((Ss / KSPLIT) / 64)   // 8

typedef short s16x8 __attribute__((ext_vector_type(8)));
typedef short s16x4 __attribute__((ext_vector_type(4)));
typedef float f32x4 __attribute__((ext_vector_type(4)));
typedef float f32x16 __attribute__((ext_vector_type(16)));

// fp32 -> bf16 (RNE) raw bits
__device__ __forceinline__ short f2bs(float f) {
    union { float f; unsigned u; } v; v.f = f;
    const unsigned r = (v.u + 0x7FFFu + ((v.u >> 16) & 1u)) >> 16;
    return (short)r;
}
__device__ __forceinline__ float bs2f(short s) {
    union { unsigned u; float f; } v; v.u = ((unsigned)(unsigned short)s) << 16;
    return v.f;
}
__device__ __forceinline__ float gelu_exact(float v) {
    return 0.5f * v * (1.0f + erff(v * 0.7071067811865475f));
}
__device__ __forceinline__ void gload16(const void* g, void* l) {
    __builtin_amdgcn_global_load_lds(
        (const __attribute__((address_space(1))) unsigned int*)g,
        (__attribute__((address_space(3))) unsigned int*)l, 16, 0, 0);
}
__device__ __forceinline__ unsigned cvt_pk(float lo, float hi) {
    unsigned r;
    asm("v_cvt_pk_bf16_f32 %0, %1, %2" : "=v"(r) : "v"(lo), "v"(hi));
    return r;
}

// ---------------------------------------------------------------------------
// Fused prep: 6 weight transposes (fp32 -> bf16, W[K][N] -> Wt[N][K]) + mask*log2e
// ---------------------------------------------------------------------------
__global__ __launch_bounds__(256) void prep(const float* __restrict__ wq, const float* __restrict__ wk,
                                            const float* __restrict__ wv, const float* __restrict__ wo,
                                            const float* __restrict__ w1, const float* __restrict__ w2,
                                            const float* __restrict__ mask,
                                            short* __restrict__ qkvw_t, short* __restrict__ wot,
                                            short* __restrict__ w1t, short* __restrict__ w2t,
                                            float* __restrict__ msc) {
    const int blk = blockIdx.x;
    const int tid = threadIdx.x;
    if (blk >= 3072) {
#pragma unroll
        for (int j = 0; j < 16; ++j) msc[tid + j * 256] = mask[tid + j * 256] * LOG2Ef;
        return;
    }
    const float* W; short* Wt; int K, N, inner;
    if (blk < 1024) {
        const int which = blk >> 8; inner = blk & 255;
        K = 1024; N = 1024;
        W = (which == 0) ? wq : (which == 1) ? wk : (which == 2) ? wv : wo;
        Wt = (which < 3) ? qkvw_t + (size_t)which * 1024 * 1024 : wot;
    } else if (blk < 2048) {
        inner = blk - 1024; K = 1024; N = 4096; W = w1; Wt = w1t;
    } else {
        inner = blk - 2048; K = 4096; N = 1024; W = w2; Wt = w2t;
    }
    const int nbx = N / 64;
    const int bx = inner % nbx, by = inner / nbx;
    __shared__ short T[64][65];
    const int n0 = bx * 64, k0 = by * 64;
    const int c = tid & 63, rg = tid >> 6;
#pragma unroll
    for (int j = 0; j < 16; ++j) {
        const int r = rg * 16 + j;
        T[r][c] = f2bs(W[(size_t)(k0 + r) * N + n0 + c]);
    }
    __syncthreads();
#pragma unroll
    for (int j = 0; j < 16; ++j) {
        const int r = rg * 16 + j;
        Wt[(size_t)(n0 + r) * K + k0 + c] = T[c][r];
    }
}

// ---------------------------------------------------------------------------
// V transpose: QKV[tok][3072] (V cols 2048..3071) -> VT[b][h][d=64][s=2048]
// ---------------------------------------------------------------------------
__global__ __launch_bounds__(256) void vtranspose(const short* __restrict__ QKV,
                                                  short* __restrict__ VT) {
    __shared__ __align__(16) short T[64 * 144];
    const int t = threadIdx.x;
    const int bh = blockIdx.x;
    const int sc = blockIdx.y;
    const int b = bh >> 4, h = bh & 15;
#pragma unroll
    for (int i = 0; i < 4; ++i) {
        const int sl = i * 32 + (t >> 3);
        const int d0 = (t & 7) * 8;
        const s16x8 v = *(const s16x8*)&QKV[((size_t)(b * Ss + sc * 128 + sl)) * 3072 + 2048 + h * 64 + d0];
#pragma unroll
        for (int e = 0; e < 8; ++e) {
            const int d = d0 + e;
            T[(d * 144 + sl) ^ (((d >> 3) & 7) << 3)] = v[e];
        }
    }
    __syncthreads();
#pragma unroll
    for (int i = 0; i < 4; ++i) {
        const int d = i * 16 + (t >> 4);
        const int s0 = (t & 15) * 8;
        const s16x8 o = *(const s16x8*)&T[(d * 144 + s0) ^ (((d >> 3) & 7) << 3)];
        *(s16x8*)&VT[((size_t)(bh * 64 + d)) * 2048 + sc * 128 + s0] = o;
    }
}

// ---------------------------------------------------------------------------
// LayerNorm: fp32 in, bf16 out
// ---------------------------------------------------------------------------
__global__ __launch_bounds__(256) void layernorm_bf16(const float* __restrict__ X,
                                                      const float* __restrict__ g,
                                                      const float* __restrict__ bta,
                                                      short* __restrict__ Y) {
    __shared__ float red[8];
    const int row = blockIdx.x;
    const int tid = threadIdx.x;
    const size_t base = (size_t)row * Dd + tid * 4;
    const float4 xv = *(const float4*)&X[base];
    float s  = xv.x + xv.y + xv.z + xv.w;
    float sq = xv.x * xv.x + xv.y * xv.y + xv.z * xv.z + xv.w * xv.w;
#pragma unroll
    for (int o = 32; o >= 1; o >>= 1) {
        s  += __shfl_xor(s, o, 64);
        sq += __shfl_xor(sq, o, 64);
    }
    const int lane = tid & 63, wv = tid >> 6;
    if (lane == 0) { red[wv] = s; red[4 + wv] = sq; }
    __syncthreads();
    const float tot  = red[0] + red[1] + red[2] + red[3];
    const float totq = red[4] + red[5] + red[6] + red[7];
    const float mu  = tot * (1.0f / Dd);
    const float var = totq * (1.0f / Dd) - mu * mu;
    const float inv = 1.0f / sqrtf(var + EPSf);
    const float4 gv = *(const float4*)&g[tid * 4];
    const float4 bv = *(const float4*)&bta[tid * 4];
    s16x4 o;
    o[0] = f2bs((xv.x - mu) * inv * gv.x + bv.x);
    o[1] = f2bs((xv.y - mu) * inv * gv.y + bv.y);
    o[2] = f2bs((xv.z - mu) * inv * gv.z + bv.z);
    o[3] = f2bs((xv.w - mu) * inv * gv.w + bv.w);
    *(s16x4*)&Y[base] = o;
}

// ---------------------------------------------------------------------------
// bf16 MFMA GEMM v2: C[M,N] = A[M,K] @ Bt[N,K]^T
// BK=64, XOR-swizzled LDS (conflict-free b128), double-buffered 2-phase,
// swapped operands (acc[n][m] = mfma(b,a)) -> vectorized C-stores.
// 4 waves in 2x2; wave tile (BM/2)x(BN/2).
// EPI: 0 = bf16 out, 1 = GELU + bf16 out, 2 = +R (fp32) -> fp32 out
// ---------------------------------------------------------------------------
template <int BM, int BN, int EPI>
__global__ __launch_bounds__(256) void gemm_v2(const short* __restrict__ A,
                                               const short* __restrict__ Bt,
                                               const float* __restrict__ R,
                                               void* __restrict__ Cout,
                                               int M, int N, int K) {
    constexpr int WM = BM / 2, WN = BN / 2;
    constexpr int MF = WM / 16, NF = WN / 16;
    __shared__ __align__(16) short As[2][BM * 64];
    __shared__ __align__(16) short Bs[2][BN * 64];

    const int tid = threadIdx.x;
    const int w = tid >> 6, l = tid & 63;
    const int lr = l & 15, lg = l >> 4;         // fragment indexing
    const int wr = w >> 1, wc = w & 1;
    const int bx = blockIdx.x, by = blockIdx.y;

    // staging lane mapping: row offset l>>3, slot l&7; source slot XOR'd
    const int srp   = l >> 3;
    const int sslot = ((l & 7) ^ (srp & 7)) * 8;
    const size_t arow0 = (size_t)(by * BM);
    const size_t brow0 = (size_t)(bx * BN);

    f32x4 acc[NF][MF] = {};

    auto STAGE = [&](int bi, int k0) {
#pragma unroll
        for (int j = 0; j < BM / 32; ++j) {
            const int r0 = w * (BM / 4) + j * 8;
            gload16(A + (arow0 + r0 + srp) * K + k0 + sslot, &As[bi][r0 * 64]);
        }
#pragma unroll
        for (int j = 0; j < BN / 32; ++j) {
            const int r0 = w * (BN / 4) + j * 8;
            gload16(Bt + (brow0 + r0 + srp) * K + k0 + sslot, &Bs[bi][r0 * 64]);
        }
    };

    STAGE(0, 0);
    int cur = 0;

    for (int k0 = 0; k0 < K; k0 += 64) {
        asm volatile("s_waitcnt vmcnt(0)" ::: "memory");
        __builtin_amdgcn_s_barrier();
        if (k0 + 64 < K) STAGE(cur ^ 1, k0 + 64);

#pragma unroll
        for (int kk = 0; kk < 2; ++kk) {
            s16x8 a[MF], b[NF];
#pragma unroll
            for (int m = 0; m < MF; ++m) {
                const int r = wr * WM + m * 16 + lr;
                a[m] = *(const s16x8*)&As[cur][r * 64 + (((kk * 4 + lg) ^ (r & 7)) * 8)];
            }
#pragma unroll
            for (int n = 0; n < NF; ++n) {
                const int r = wc * WN + n * 16 + lr;
                b[n] = *(const s16x8*)&Bs[cur][r * 64 + (((kk * 4 + lg) ^ (r & 7)) * 8)];
            }
#pragma unroll
            for (int n = 0; n < NF; ++n)
#pragma unroll
                for (int m = 0; m < MF; ++m)
                    acc[n][m] = __builtin_amdgcn_mfma_f32_16x16x32_bf16(b[n], a[m], acc[n][m], 0, 0, 0);
        }
        cur ^= 1;
    }

    // epilogue: lane holds C[row0+m*16+lr][col0+n*16+lg*4 + r], r=0..3
    const int row0 = by * BM + wr * WM;
    const int col0 = bx * BN + wc * WN;
#pragma unroll
    for (int m = 0; m < MF; ++m) {
        const int row = row0 + m * 16 + lr;
#pragma unroll
        for (int n = 0; n < NF; ++n) {
            const int cb = col0 + n * 16 + lg * 4;
            if (EPI == 2) {
                float* C = (float*)Cout;
                const f32x4 r4 = *(const f32x4*)&R[(size_t)row * N + cb];
                f32x4 o;
#pragma unroll
                for (int r = 0; r < 4; ++r) o[r] = acc[n][m][r] + r4[r];
                *(f32x4*)&C[(size_t)row * N + cb] = o;
            } else {
                s16x4 o;
#pragma unroll
                for (int r = 0; r < 4; ++r) {
                    float v = acc[n][m][r];
                    if (EPI == 1) v = gelu_exact(v);
                    o[r] = f2bs(v);
                }
                *(s16x4*)&((short*)Cout)[(size_t)row * N + cb] = o;
            }
        }
    }
}

// ---------------------------------------------------------------------------
// Flash attention: 32x32x16 MFMA, swapped operands, in-register P.
// Block = 4 waves x 32 q = 128 q. KSPLIT=4 (8 k-tiles of 64 per part).
// K AND V staged in LDS (dbuf, gload_lds w16, XOR source swizzle).
// ---------------------------------------------------------------------------
__global__ __launch_bounds__(256) void attn_split(const short* __restrict__ QKV,
                                                  const short* __restrict__ VT,
                                                  const float* __restrict__ MSC,
                                                  short* __restrict__ Opart,
                                                  float2* __restrict__ ML) {
    __shared__ __align__(16) short Kbuf[2][64 * 64];
    __shared__ __align__(16) short Vbuf[2][64 * 64];

    const int tid = threadIdx.x;
    const int w = tid >> 6, l = tid & 63;
    const int col = l & 31;
    const int hi = l >> 5;

    const int bid = blockIdx.x;
    const int part = bid >> 9;            // 0..3
    const int inner = bid & 511;
    const int qt = inner & 15, h = (inner >> 4) & 15, b = inner >> 8;
    const int q0 = qt * 128 + w * 32;
    const int k_base = part * (Ss / KSPLIT);

    s16x8 qf[4];
    {
        const short* qsrc = QKV + ((size_t)(b * Ss + q0 + col)) * 3072 + h * 64 + hi * 8;
        qf[0] = *(const s16x8*)(qsrc);
        qf[1] = *(const s16x8*)(qsrc + 16);
        qf[2] = *(const s16x8*)(qsrc + 32);
        qf[3] = *(const s16x8*)(qsrc + 48);
    }

    const int sr   = l >> 3;
    const int slot = ((l & 7) ^ (sr & 7)) * 8;
    const short* kg = QKV + (size_t)(b * Ss) * 3072 + 1024 + h * 64 + (size_t)sr * 3072 + slot;
    const short* vg = VT + ((size_t)(b * Hh + h) * 64 + sr) * 2048 + k_base + slot;
    const float* mscb = MSC + (size_t)b * Ss + k_base;

    f32x16 o_acc[2] = {};
    float m_used = -1e30f, l_run = 0.0f;

    auto STAGE = [&](int bi, int t) {
#pragma unroll
        for (int j = 0; j < 2; ++j) {
            const int r0 = w * 16 + j * 8;
            gload16(kg + (size_t)(k_base + t * 64 + r0) * 3072, &Kbuf[bi][r0 * 64]);
            gload16(vg + (size_t)r0 * 2048 + t * 64,             &Vbuf[bi][r0 * 64]);
        }
    };

    STAGE(0, 0);
    int cur = 0;

    for (int i = 0; i < NTILES; ++i) {
        asm volatile("s_waitcnt vmcnt(0)" ::: "memory");
        __builtin_amdgcn_s_barrier();
        if (i + 1 < NTILES) STAGE(cur ^ 1, i + 1);

#pragma unroll
        for (int sub = 0; sub < 2; ++sub) {
            f32x16 sa = {};
            const int rk = sub * 32 + col;
#pragma unroll
            for (int dd = 0; dd < 4; ++dd) {
                const s16x8 kf = *(const s16x8*)&Kbuf[cur][rk * 64 + ((2 * dd + hi) ^ (rk & 7)) * 8];
                sa = __builtin_amdgcn_mfma_f32_32x32x16_bf16(kf, qf[dd], sa, 0, 0, 0);
            }

#pragma unroll
            for (int c4 = 0; c4 < 4; ++c4) {
                const f32x4 mv = *(const f32x4*)&mscb[i * 64 + sub * 32 + 8 * c4 + 4 * hi];
#pragma unroll
                for (int rr = 0; rr < 4; ++rr) sa[c4 * 4 + rr] = sa[c4 * 4 + rr] * SCALE2f + mv[rr];
            }
            float t8[8], t4[4];
#pragma unroll
            for (int r = 0; r < 8; ++r) t8[r] = fmaxf(sa[2 * r], sa[2 * r + 1]);
#pragma unroll
            for (int r = 0; r < 4; ++r) t4[r] = fmaxf(t8[2 * r], t8[2 * r + 1]);
            float tmax = fmaxf(fmaxf(t4[0], t4[1]), fmaxf(t4[2], t4[3]));
            {
                unsigned a = __float_as_uint(tmax), bq = __float_as_uint(tmax);
                asm volatile("v_permlane32_swap_b32 %0, %1" : "+v"(a), "+v"(bq));
                tmax = fmaxf(tmax, __uint_as_float(hi ? a : bq));
            }
            if (__any(tmax > m_used + 8.0f)) {
                const float nm = fmaxf(m_used, tmax);
                const float corr = __builtin_amdgcn_exp2f(m_used - nm);
                m_used = nm;
                l_run *= corr;
#pragma unroll
                for (int dt = 0; dt < 2; ++dt)
#pragma unroll
                    for (int r = 0; r < 16; ++r) o_acc[dt][r] *= corr;
            }

            unsigned wd[8];
            float s8[8];
#pragma unroll
            for (int m8 = 0; m8 < 8; ++m8) {
                const float p0 = __builtin_amdgcn_exp2f(sa[2 * m8]     - m_used);
                const float p1 = __builtin_amdgcn_exp2f(sa[2 * m8 + 1] - m_used);
                s8[m8] = p0 + p1;
                wd[m8] = cvt_pk(p0, p1);
            }
            float s4[4];
#pragma unroll
            for (int r = 0; r < 4; ++r) s4[r] = s8[2 * r] + s8[2 * r + 1];
            l_run += (s4[0] + s4[1]) + (s4[2] + s4[3]);

            unsigned f00 = wd[0], f02 = wd[2];
            asm volatile("v_permlane32_swap_b32 %0, %1" : "+v"(f00), "+v"(f02));
            unsigned f01 = wd[1], f03 = wd[3];
            asm volatile("v_permlane32_swap_b32 %0, %1" : "+v"(f01), "+v"(f03));
            unsigned f10 = wd[4], f12 = wd[6];
            asm volatile("v_permlane32_swap_b32 %0, %1" : "+v"(f10), "+v"(f12));
            unsigned f11 = wd[5], f13 = wd[7];
            asm volatile("v_permlane32_swap_b32 %0, %1" : "+v"(f11), "+v"(f13));
            union { unsigned u[4]; s16x8 v; } pf0, pf1;
            pf0.u[0] = f00; pf0.u[1] = f01; pf0.u[2] = f02; pf0.u[3] = f03;
            pf1.u[0] = f10; pf1.u[1] = f11; pf1.u[2] = f12; pf1.u[3] = f13;

#pragma unroll
            for (int dt = 0; dt < 2; ++dt) {
                const int rv = dt * 32 + col;
                const s16x8 v0 = *(const s16x8*)&Vbuf[cur][rv * 64 + ((sub * 4 + 0 + hi) ^ (rv & 7)) * 8];
                const s16x8 v1 = *(const s16x8*)&Vbuf[cur][rv * 64 + ((sub * 4 + 2 + hi) ^ (rv & 7)) * 8];
                o_acc[dt] = __builtin_amdgcn_mfma_f32_32x32x16_bf16(v0, pf0.v, o_acc[dt], 0, 0, 0);
                o_acc[dt] = __builtin_amdgcn_mfma_f32_32x32x16_bf16(v1, pf1.v, o_acc[dt], 0, 0, 0);
            }
        }
        cur ^= 1;
    }

    float l_tot;
    {
        unsigned a = __float_as_uint(l_run), bq = __float_as_uint(l_run);
        asm volatile("v_permlane32_swap_b32 %0, %1" : "+v"(a), "+v"(bq));
        l_tot = l_run + __uint_as_float(hi ? a : bq);
    }
    const size_t tok = (size_t)(b * Ss + q0 + col);
    if (hi == 0) {
        ML[(size_t)part * (Bb * Ss * Hh) + tok * Hh + h] = make_float2(m_used, l_tot);
    }
    short* obase = Opart + (size_t)part * (Bb * Ss) * Dd + tok * Dd + h * 64;
#pragma unroll
    for (int dt = 0; dt < 2; ++dt) {
#pragma unroll
        for (int c4 = 0; c4 < 4; ++c4) {
            s16x4 ov;
#pragma unroll
            for (int rr = 0; rr < 4; ++rr) ov[rr] = f2bs(o_acc[dt][c4 * 4 + rr]);
            *(s16x4*)&obase[dt * 32 + 8 * c4 + 4 * hi] = ov;
        }
    }
}

// ---------------------------------------------------------------------------
// KSPLIT combine
// ---------------------------------------------------------------------------
__global__ __launch_bounds__(256) void attn_combine(const short* __restrict__ Opart,
                                                    const float2* __restrict__ ML,
                                                    short* __restrict__ Oa) {
    const int tok = blockIdx.x;
    const int t = threadIdx.x;
    const int h = t >> 4;
    const int d = (t & 15) * 4;
    float2 ml[KSPLIT];
    float M = -1e30f;
#pragma unroll
    for (int p = 0; p < KSPLIT; ++p) {
        ml[p] = ML[(size_t)p * (Bb * Ss * Hh) + (size_t)tok * Hh + h];
        M = fmaxf(M, ml[p].x);
    }
    float a[KSPLIT], denom = 0.0f;
#pragma unroll
    for (int p = 0; p < KSPLIT; ++p) {
        a[p] = __builtin_amdgcn_exp2f(ml[p].x - M);
        denom += ml[p].y * a[p];
    }
    const float inv = 1.0f / denom;
    const size_t off = (size_t)tok * Dd + h * 64 + d;
    float acc[4] = {};
#pragma unroll
    for (int p = 0; p < KSPLIT; ++p) {
        const s16x4 o4 = *(const s16x4*)&Opart[(size_t)p * (Bb * Ss) * Dd + off];
#pragma unroll
        for (int r = 0; r < 4; ++r) acc[r] += bs2f(o4[r]) * a[p];
    }
    s16x4 o;
#pragma unroll
    for (int r = 0; r < 4; ++r) o[r] = f2bs(acc[r] * inv);
    *(s16x4*)&Oa[off] = o;
}

// ---------------------------------------------------------------------------
extern "C" void kernel_launch(void* const* d_in, const int* in_sizes, int n_in,
                              void* d_out, int out_size, void* d_ws, size_t ws_size,
                              hipStream_t stream) {
    const float* x    = (const float*)d_in[0];
    const float* mask = (const float*)d_in[1];
    const float* wq   = (const float*)d_in[2];
    const float* wk   = (const float*)d_in[3];
    const float* wv   = (const float*)d_in[4];
    const float* wo   = (const float*)d_in[5];
    const float* w1   = (const float*)d_in[6];
    const float* w2   = (const float*)d_in[7];
    const float* ln1g = (const float*)d_in[8];
    const float* ln1b = (const float*)d_in[9];
    const float* ln2g = (const float*)d_in[10];
    const float* ln2b = (const float*)d_in[11];
    float* out = (float*)d_out;

    char* p = (char*)d_ws;
    short* qkvw_t = (short*)p; p += (size_t)3072 * 1024 * 2;   // 6 MB
    short* wot    = (short*)p; p += (size_t)1024 * 1024 * 2;   // 2 MB
    short* w1t    = (short*)p; p += (size_t)4096 * 1024 * 2;   // 8 MB
    short* w2t    = (short*)p; p += (size_t)1024 * 4096 * 2;   // 8 MB
    short* y_bf   = (short*)p; p += (size_t)4096 * 1024 * 2;   // 8 MB
    short* qkv    = (short*)p; p += (size_t)4096 * 3072 * 2;   // 24 MB
    short* attn_b = (short*)p; p += (size_t)4096 * 1024 * 2;   // 8 MB
    short* y2_bf  = (short*)p; p += (size_t)4096 * 1024 * 2;   // 8 MB
    char*  hregion = p;        p += (size_t)4096 * 4096 * 2;   // 32 MB
    float* msc    = (float*)p; p += (size_t)Bb * Ss * 4;       // 16 KB

    short*  h_bf   = (short*)hregion;
    short*  o_part = (short*)hregion;           // 32 MB (dead before FFN)
    short*  vt     = y_bf;                      // y_bf dead after QKV GEMM
    float2* ml     = (float2*)qkvw_t;           // qkvw_t dead after QKV GEMM

    const int M = Bb * Ss;  // 4096

    prep<<<3073, 256, 0, stream>>>(wq, wk, wv, wo, w1, w2, mask, qkvw_t, wot, w1t, w2t, msc);
    layernorm_bf16<<<M, 256, 0, stream>>>(x, ln1g, ln1b, y_bf);
    gemm_v2<128, 128, 0><<<dim3(24, 32), 256, 0, stream>>>(y_bf, qkvw_t, nullptr, qkv, M, 3072, 1024);
    vtranspose<<<dim3(32, 16), 256, 0, stream>>>(qkv, vt);
    attn_split<<<KSPLIT * 512, 256, 0, stream>>>(qkv, vt, msc, o_part, ml);
    attn_combine<<<M, 256, 0, stream>>>(o_part, ml, attn_b);
    gemm_v2<64, 128, 2><<<dim3(8, 64), 256, 0, stream>>>(attn_b, wot, x, out, M, 1024, 1024);
    layernorm_bf16<<<M, 256, 0, stream>>>(out, ln2g, ln2b, y2_bf);
    gemm_v2<128, 128, 1><<<dim3(32, 32), 256, 0, stream>>>(y2_bf, w1t, nullptr, h_bf, M, 4096, 1024);
    gemm_v2<64, 128, 2><<<dim3(8, 64), 256, 0, stream>>>(h_bf, w2t, out, out, M, 1024, 4096);
}